// Round 11
// baseline (47859.296 us; speedup 1.0000x reference)
//
#include <hip/hip_runtime.h>

#define Bx 128
#define Sx 512
#define Fx 64
#define Hx 512
#define Xx 128   // 2F

// ---- workspace float offsets ----
#define PARTB_OFF 0ull                             // bwd Wout-partial [B][S][F]
#define H_OFF     ((size_t)Bx * Sx * Fx)           // h [2dir][2ping][b128][u512]
#define BAR_OFF   (H_OFF + (size_t)2 * 2 * Bx * Hx)// 4096 ints: 8 grp x 32 slot x 16
#define FLAG_OFF  (BAR_OFF + 4096)

// ---- LDS word offsets ----
#define LDSW_WHH   0                           // [3][16][8][68] = 26112 floats
#define LDSW_XIN   26112                       // [32 b][8 chunks][20] = 5120
#define LDSW_HX    (LDSW_XIN + 5120)           // h bounce [32 b][16 u] = 512
#define LDSW_TOTAL (LDSW_HX + 512 + 16)        // 31760 floats = 127 KB -> 1 wg/CU

struct BParams {
  const float* x; const void* mask;
  const float* Wih_f; const float* Whh_f; const float* bih_f; const float* bhh_f;
  const float* Wro_f; const float* bro_f;
  const float* Wih_b; const float* Whh_b; const float* bih_b; const float* bhh_b;
  const float* Wro_b; const float* bro_b;
  const float* Wout; const float* bout;
  float* out; float* ws;
};

__global__ void detect_kernel(const unsigned int* mask, float* ws) {
  int* bars = (int*)(ws + BAR_OFF);
  int* flag = (int*)(ws + FLAG_OFF);
  int t = threadIdx.x;
  for (int i = t; i < 4096; i += blockDim.x) bars[i] = 0;
  if (t == 0) *flag = 0;
  __syncthreads();
  unsigned int v = 0;
  for (int i = t; i < 4096; i += blockDim.x) v |= mask[i] & 0xFFFFFF00u;
  if (v) atomicOr(flag, 1);
}

__global__ void combine_kernel(float* out, const float* partb, const float* bout) {
  int i = blockIdx.x * blockDim.x + threadIdx.x;
  out[i] = out[i] + partb[i] + bout[i & 63];
}

__device__ __forceinline__ void fma4(float& a, float4 w, float4 h) {
  a = fmaf(w.x, h.x, a); a = fmaf(w.y, h.y, a);
  a = fmaf(w.z, h.z, a); a = fmaf(w.w, h.w, a);
}

__device__ __forceinline__ float sel8(const float* a, int idx) {
  float v = a[0];
#pragma unroll
  for (int i = 1; i < 8; ++i) v = (idx == i) ? a[i] : v;
  return v;
}

// System-scope relaxed store: write-through past L2 (proven rounds 7-10).
__device__ __forceinline__ void st_sys(float* p, float v) {
  __hip_atomic_store(p, v, __ATOMIC_RELAXED, __HIP_MEMORY_SCOPE_SYSTEM);
}
__device__ __forceinline__ void st_sys_i(int* p, int v) {
  __hip_atomic_store(p, v, __ATOMIC_RELAXED, __HIP_MEMORY_SCOPE_SYSTEM);
}

// 32-member group barrier (R9 slot protocol + R10 buffer_inv acquire, proven).
__device__ __forceinline__ void gbar(int* slots, int hs, int nbar) {
  __syncthreads();   // vmcnt(0): all waves' st_sys data at coherence point
  if (threadIdx.x < 64) {
    if (threadIdx.x == 0) st_sys_i(slots + hs * 16, nbar);
    const int* myslot = slots + (threadIdx.x & 31) * 16;
    for (;;) {
      int v = __hip_atomic_load(myslot, __ATOMIC_RELAXED, __HIP_MEMORY_SCOPE_AGENT);
      if (__all(v >= nbar)) break;
      __builtin_amdgcn_s_sleep(1);
    }
    asm volatile("buffer_inv\n\ts_waitcnt vmcnt(0)" ::: "memory");
  }
  __syncthreads();
}

__global__ void __launch_bounds__(512, 2)
birnn_main(BParams p) {
  extern __shared__ float lds[];

  const int w   = blockIdx.x;
  const int g   = w & 7;         // group = (dir, batch-group)
  const int dir = g >> 2;
  const int bg  = g & 3;
  const int hs  = w >> 3;        // hidden slice 0..31 (= slot index)
  const int b0  = bg * 32;
  const int u0  = hs * 16;
  const int tid = threadIdx.x;

  const float* Wih = dir ? p.Wih_b : p.Wih_f;
  const float* Whh = dir ? p.Whh_b : p.Whh_f;
  const float* bih = dir ? p.bih_b : p.bih_f;
  const float* bhh = dir ? p.bhh_b : p.bhh_f;
  const float* Wro = dir ? p.Wro_b : p.Wro_f;
  const float* bro = dir ? p.bro_b : p.bro_f;

  float* hbuf  = p.ws + H_OFF;   // [dir*2+ping][b(128)][u(512)]
  int*   slots = (int*)(p.ws + BAR_OFF) + g * 512;
  const int u8f = *(const int*)(p.ws + FLAG_OFF);
  const unsigned char* m8  = (const unsigned char*)p.mask;
  const int*           m32 = (const int*)p.mask;

  float* pout   = dir ? (p.ws + PARTB_OFF) : p.out;  // Wout half-partials
  float* out_xh = p.out + (size_t)(1 + dir) * Bx * Sx * Fx;

  // ---- preload LDS-resident Whh slice ----
  for (int idx = tid; idx < 3 * 16 * 512; idx += 512) {
    int g3 = idx >> 13; int rem = idx & 8191;
    int u = rem >> 9;   int j = rem & 511;
    lds[LDSW_WHH + ((g3 * 16 + u) * 8 + (j >> 6)) * 68 + (j & 63)] =
        Whh[(size_t)(g3 * 512 + u0 + u) * Hx + j];
  }

  // ---- init: h_0 = 0 (staging at k=1 derives xhat_0 = bro from it) ----
  if (hs == 0) {
    for (int idx = tid; idx < 32 * 512; idx += 512) {
      int bl = idx >> 4, ul = idx & 15;           // 16 consecutive floats / b
      // cover [32 b][512 u]: idx = bl*16+ul over 512-thread strides -> loop
    }
    for (int idx = tid; idx < 32 * 512; idx += 512) {
      int b = b0 + (idx >> 9), j = idx & 511;
      st_sys(&hbuf[((size_t)(dir * 2 + 0) * Bx + b) * Hx + j], 0.f);
    }
  }

  // ---- phase-A map (unchanged): lane = jq x ulo; wave = bsub x uhi ----
  const int jq   = tid & 7;
  const int ulo  = (tid >> 3) & 7;
  const int wv   = tid >> 6;
  const int bsub = wv & 3;
  const int uhi  = wv >> 2;
  const int u    = uhi * 8 + ulo;
  const int bA   = b0 + bsub * 8;
  const int ru   = u0 + u;
  const int j0   = jq * 64;

  // ---- staging map: wave = sbsub(2b) x sfh(1b); lane = sfq(3b) x sbo(3b) ----
  const int sbo   = tid & 7;
  const int sfq   = (tid >> 3) & 7;
  const int sbl   = (wv & 3) * 8 + sbo;          // batch-local 0..31
  const int b_st  = b0 + sbl;
  const int fbase = (wv >> 2) * 32 + sfq * 4;    // 0..60 step 4
  const int b_own = b0 + hs;
  const bool ownb = (sbl == hs);
  const bool pwave = ((wv & 3) == 0);            // waves 0,4 compute pout

  // per-thread-invariant weights/biases in registers
  float4 wih0[4], wih1[4], wih2[4];
#pragma unroll
  for (int q = 0; q < 4; ++q) {
    wih0[q] = *(const float4*)(Wih + (size_t)(0 * 512 + ru) * Xx + jq * 16 + q * 4);
    wih1[q] = *(const float4*)(Wih + (size_t)(1 * 512 + ru) * Xx + jq * 16 + q * 4);
    wih2[q] = *(const float4*)(Wih + (size_t)(2 * 512 + ru) * Xx + jq * 16 + q * 4);
  }
  const float bs_r = bih[ru] + bhh[ru];
  const float bs_z = bih[512 + ru] + bhh[512 + ru];
  const float bs_i = bih[1024 + ru];
  const float bs_h = bhh[1024 + ru];

  const float* w0p = lds + LDSW_WHH + ((0 * 16 + u) * 8 + jq) * 68;
  const float* w1p = lds + LDSW_WHH + ((1 * 16 + u) * 8 + jq) * 68;
  const float* w2p = lds + LDSW_WHH + ((2 * 16 + u) * 8 + jq) * 68;

  // staging weight row pointers + biases
  const float* wroP0 = Wro + (size_t)(fbase + 0) * Hx;
  const float* wroP1 = Wro + (size_t)(fbase + 1) * Hx;
  const float* wroP2 = Wro + (size_t)(fbase + 2) * Hx;
  const float* wroP3 = Wro + (size_t)(fbase + 3) * Hx;
  const float4 bro4  = *(const float4*)(bro + fbase);
  const float* woutP0 = p.Wout + (size_t)(fbase + 0) * (2 * Hx) + dir * Hx;
  const float* woutP1 = p.Wout + (size_t)(fbase + 1) * (2 * Hx) + dir * Hx;
  const float* woutP2 = p.Wout + (size_t)(fbase + 2) * (2 * Hx) + dir * Hx;
  const float* woutP3 = p.Wout + (size_t)(fbase + 3) * (2 * Hx) + dir * Hx;

  float hprev_own = 0.f;   // h[bA+jq][ru], written by this thread every step

  int nbar = 0;

  for (int k = 1; k < Sx; ++k) {
    const int pp = k & 1, pr = pp ^ 1;
    const int t_in = dir ? (Sx - k) : (k - 1);

    // ---- prefetch x/mask (read-only; overlaps barrier wait) ----
    size_t xbase = ((size_t)b_st * Sx + t_in) * Fx + fbase;
    float4 xq = *(const float4*)(p.x + xbase);
    int mi0, mi1, mi2, mi3;
    if (u8f) {
      unsigned mm = *(const unsigned*)(m8 + xbase);
      mi0 = mm & 0xFF; mi1 = (mm >> 8) & 0xFF;
      mi2 = (mm >> 16) & 0xFF; mi3 = (mm >> 24) & 0xFF;
    } else {
      int4 mv = *(const int4*)(m32 + xbase);
      mi0 = mv.x; mi1 = mv.y; mi2 = mv.z; mi3 = mv.w;
    }

    ++nbar;
    gbar(slots, hs, nbar);   // h_{k-1} visible group-wide

    // ---- staging: redundant xhat = Wro @ h_{k-1} for own 32 batches ----
    {
      const float* hrow = hbuf + ((size_t)(dir * 2 + pr) * Bx + b_st) * Hx;
      float a0 = 0.f, a1 = 0.f, a2 = 0.f, a3 = 0.f;
#pragma unroll 4
      for (int j = 0; j < Hx; j += 4) {
        float4 h4 = *(const float4*)(hrow + j);
        float4 q0 = *(const float4*)(wroP0 + j);
        float4 q1 = *(const float4*)(wroP1 + j);
        float4 q2 = *(const float4*)(wroP2 + j);
        float4 q3 = *(const float4*)(wroP3 + j);
        fma4(a0, q0, h4); fma4(a1, q1, h4);
        fma4(a2, q2, h4); fma4(a3, q3, h4);
      }
      float xh0 = a0 + bro4.x, xh1 = a1 + bro4.y;
      float xh2 = a2 + bro4.z, xh3 = a3 + bro4.w;

      float* xr = lds + LDSW_XIN + sbl * 160 + (fbase >> 4) * 20 + (fbase & 15);
      *(float4*)xr = make_float4(mi0 ? xq.x : xh0, mi1 ? xq.y : xh1,
                                 mi2 ? xq.z : xh2, mi3 ? xq.w : xh3);
      float* mr = lds + LDSW_XIN + sbl * 160 + ((64 + fbase) >> 4) * 20 + (fbase & 15);
      *(float4*)mr = make_float4((float)mi0, (float)mi1, (float)mi2, (float)mi3);

      if (ownb)   // this wg's assigned batch: write xh output (T = t_in)
        *(float4*)(out_xh + ((size_t)b_own * Sx + t_in) * Fx + fbase) =
            make_float4(xh0, xh1, xh2, xh3);

      if (pwave) {  // Wout half-partial for assigned batch, j-split by sbo
        const float* hop = hbuf + ((size_t)(dir * 2 + pr) * Bx + b_own) * Hx + sbo * 64;
        float p0 = 0.f, p1 = 0.f, p2 = 0.f, p3 = 0.f;
#pragma unroll 4
        for (int jj = 0; jj < 64; jj += 4) {
          float4 h4 = *(const float4*)(hop + jj);
          float4 q0 = *(const float4*)(woutP0 + sbo * 64 + jj);
          float4 q1 = *(const float4*)(woutP1 + sbo * 64 + jj);
          float4 q2 = *(const float4*)(woutP2 + sbo * 64 + jj);
          float4 q3 = *(const float4*)(woutP3 + sbo * 64 + jj);
          fma4(p0, q0, h4); fma4(p1, q1, h4);
          fma4(p2, q2, h4); fma4(p3, q3, h4);
        }
#pragma unroll
        for (int m = 1; m <= 4; m <<= 1) {
          p0 += __shfl_xor(p0, m); p1 += __shfl_xor(p1, m);
          p2 += __shfl_xor(p2, m); p3 += __shfl_xor(p3, m);
        }
        if (sbo == 0)
          *(float4*)(pout + ((size_t)b_own * Sx + t_in) * Fx + fbase) =
              make_float4(p0, p1, p2, p3);
      }
    }
    __syncthreads();

    // ---- phase A: gates ----
    float acc0[8], acc1[8], acc2[8], acc3[8];
#pragma unroll
    for (int i = 0; i < 8; ++i) { acc0[i] = 0.f; acc1[i] = 0.f; acc2[i] = 0.f; acc3[i] = 0.f; }

    {
      const float* hrd = hbuf + (size_t)(dir * 2 + pr) * Bx * Hx;
#pragma unroll 2
      for (int jj = 0; jj < 64; jj += 4) {
        float4 w0 = *(const float4*)(w0p + jj);
        float4 w1 = *(const float4*)(w1p + jj);
        float4 w2 = *(const float4*)(w2p + jj);
#pragma unroll
        for (int bb = 0; bb < 8; ++bb) {
          float4 h4 = *(const float4*)(hrd + (size_t)(bA + bb) * Hx + j0 + jj);
          fma4(acc0[bb], w0, h4);
          fma4(acc1[bb], w1, h4);
          fma4(acc3[bb], w2, h4);
        }
      }
    }
    {
      const float* xinb = lds + LDSW_XIN;
#pragma unroll
      for (int q = 0; q < 4; ++q) {
        float4 w0 = wih0[q], w1 = wih1[q], w2 = wih2[q];
        int off = jq * 20 + q * 4;
#pragma unroll
        for (int bb = 0; bb < 8; ++bb) {
          float4 xv = *(const float4*)(xinb + (bsub * 8 + bb) * 160 + off);
          fma4(acc0[bb], w0, xv);
          fma4(acc1[bb], w1, xv);
          fma4(acc2[bb], w2, xv);
        }
      }
    }
#pragma unroll
    for (int m = 1; m <= 4; m <<= 1) {
#pragma unroll
      for (int bb = 0; bb < 8; ++bb) {
        acc0[bb] += __shfl_xor(acc0[bb], m);
        acc1[bb] += __shfl_xor(acc1[bb], m);
        acc2[bb] += __shfl_xor(acc2[bb], m);
        acc3[bb] += __shfl_xor(acc3[bb], m);
      }
    }
    {
      float sr  = sel8(acc0, jq);
      float sz  = sel8(acc1, jq);
      float sgi = sel8(acc2, jq);
      float sgh = sel8(acc3, jq);
      float r = 1.f / (1.f + __expf(-(sr + bs_r)));
      float z = 1.f / (1.f + __expf(-(sz + bs_z)));
      float n = tanhf(sgi + bs_i + r * (sgh + bs_h));
      float hn = (1.f - z) * n + z * hprev_own;
      hprev_own = hn;
      lds[LDSW_HX + (bsub * 8 + jq) * 16 + u] = hn;   // bounce for coalescing
    }
    __syncthreads();

    // ---- h_k store: [b][u], 64B contiguous runs, system-scope ----
    st_sys(&hbuf[((size_t)(dir * 2 + pp) * Bx + b0 + (tid >> 4)) * Hx + u0 + (tid & 15)],
           lds[LDSW_HX + tid]);
  }

  // ---- epilogue: outputs from h_{S-1} (T = dir ? 0 : S-1) ----
  ++nbar;
  gbar(slots, hs, nbar);
  {
    const int prE = (Sx - 1) & 1;
    const int tE  = dir ? 0 : (Sx - 1);
    const float* hrow = hbuf + ((size_t)(dir * 2 + prE) * Bx + b_own) * Hx;
    if (ownb) {
      float a0 = 0.f, a1 = 0.f, a2 = 0.f, a3 = 0.f;
#pragma unroll 4
      for (int j = 0; j < Hx; j += 4) {
        float4 h4 = *(const float4*)(hrow + j);
        float4 q0 = *(const float4*)(wroP0 + j);
        float4 q1 = *(const float4*)(wroP1 + j);
        float4 q2 = *(const float4*)(wroP2 + j);
        float4 q3 = *(const float4*)(wroP3 + j);
        fma4(a0, q0, h4); fma4(a1, q1, h4);
        fma4(a2, q2, h4); fma4(a3, q3, h4);
      }
      *(float4*)(out_xh + ((size_t)b_own * Sx + tE) * Fx + fbase) =
          make_float4(a0 + bro4.x, a1 + bro4.y, a2 + bro4.z, a3 + bro4.w);
    }
    if (pwave) {
      const float* hop = hrow + sbo * 64;
      float p0 = 0.f, p1 = 0.f, p2 = 0.f, p3 = 0.f;
#pragma unroll 4
      for (int jj = 0; jj < 64; jj += 4) {
        float4 h4 = *(const float4*)(hop + jj);
        float4 q0 = *(const float4*)(woutP0 + sbo * 64 + jj);
        float4 q1 = *(const float4*)(woutP1 + sbo * 64 + jj);
        float4 q2 = *(const float4*)(woutP2 + sbo * 64 + jj);
        float4 q3 = *(const float4*)(woutP3 + sbo * 64 + jj);
        fma4(p0, q0, h4); fma4(p1, q1, h4);
        fma4(p2, q2, h4); fma4(p3, q3, h4);
      }
#pragma unroll
      for (int m = 1; m <= 4; m <<= 1) {
        p0 += __shfl_xor(p0, m); p1 += __shfl_xor(p1, m);
        p2 += __shfl_xor(p2, m); p3 += __shfl_xor(p3, m);
      }
      if (sbo == 0)
        *(float4*)(pout + ((size_t)b_own * Sx + tE) * Fx + fbase) =
            make_float4(p0, p1, p2, p3);
    }
  }
}

extern "C" void kernel_launch(void* const* d_in, const int* in_sizes, int n_in,
                              void* d_out, int out_size, void* d_ws, size_t ws_size,
                              hipStream_t stream) {
  (void)in_sizes; (void)n_in; (void)out_size; (void)ws_size;
  float* ws = (float*)d_ws;

  detect_kernel<<<1, 512, 0, stream>>>((const unsigned int*)d_in[1], ws);

  BParams p;
  p.x     = (const float*)d_in[0];  p.mask = d_in[1];
  p.Wih_f = (const float*)d_in[2];  p.Whh_f = (const float*)d_in[3];
  p.bih_f = (const float*)d_in[4];  p.bhh_f = (const float*)d_in[5];
  p.Wro_f = (const float*)d_in[6];  p.bro_f = (const float*)d_in[7];
  p.Wih_b = (const float*)d_in[8];  p.Whh_b = (const float*)d_in[9];
  p.bih_b = (const float*)d_in[10]; p.bhh_b = (const float*)d_in[11];
  p.Wro_b = (const float*)d_in[12]; p.bro_b = (const float*)d_in[13];
  p.Wout  = (const float*)d_in[14]; p.bout  = (const float*)d_in[15];
  p.out   = (float*)d_out;
  p.ws    = ws;

  hipFuncSetAttribute(reinterpret_cast<const void*>(birnn_main),
                      hipFuncAttributeMaxDynamicSharedMemorySize,
                      (int)(LDSW_TOTAL * sizeof(float)));
  void* args[] = { (void*)&p };
  hipLaunchCooperativeKernel(reinterpret_cast<void*>(birnn_main),
                             dim3(256), dim3(512), args,
                             (unsigned)(LDSW_TOTAL * sizeof(float)), stream);

  combine_kernel<<<dim3(Bx * Sx * Fx / 256), dim3(256), 0, stream>>>(
      (float*)d_out, ws + PARTB_OFF, (const float*)d_in[15]);
}

// Round 14
// 21131.337 us; speedup vs baseline: 2.2648x; 2.2648x over previous
//
#include <hip/hip_runtime.h>

#define Bx 128
#define Sx 512
#define Fx 64
#define Hx 512
#define Xx 128   // 2F

// ---- workspace float offsets ----
#define PARTB_OFF 0ull                               // bwd Wout-partial [B][S][F]
#define H_OFF     ((size_t)Bx * Sx * Fx)             // h [2dir*2ping][u][b]
#define XHB_OFF   (H_OFF + (size_t)2 * 2 * Hx * Bx)  // xhat acc [4 ping][2 dir][b][f]
#define BAR_OFF   (XHB_OFF + (size_t)4 * 2 * Bx * Fx)
#define FLAG_OFF  (BAR_OFF + 4096)

// ---- LDS word offsets ----
#define LDSW_WHH   0                            // [3][16][8][68] = 26112
#define LDSW_XIN   26112                        // [32 b][8 chunks][20] = 5120
#define LDSW_WRO   (LDSW_XIN + 32 * 160)        // full rows (epilogue) 2x544
#define LDSW_WOUT  (LDSW_WRO + 2 * 544)         // full rows (pout) 2x544
#define LDSW_WROS  (LDSW_WOUT + 2 * 544)        // Wro slice [64 f][17] = 1088
#define LDSW_HX    (LDSW_WROS + 1088)           // h slice bounce [32 b][16 u]
#define LDSW_TOTAL (LDSW_HX + 512 + 16)         // 35024 floats = 140KB -> 1 wg/CU

struct BParams {
  const float* x; const void* mask;
  const float* Wih_f; const float* Whh_f; const float* bih_f; const float* bhh_f;
  const float* Wro_f; const float* bro_f;
  const float* Wih_b; const float* Whh_b; const float* bih_b; const float* bhh_b;
  const float* Wro_b; const float* bro_b;
  const float* Wout; const float* bout;
  float* out; float* ws;
};

__global__ void detect_kernel(const unsigned int* mask, float* ws) {
  int* bars = (int*)(ws + BAR_OFF);
  int* flag = (int*)(ws + FLAG_OFF);
  int t = threadIdx.x;
  for (int i = t; i < 4096; i += blockDim.x) bars[i] = 0;
  if (t == 0) *flag = 0;
  __syncthreads();
  unsigned int v = 0;
  for (int i = t; i < 4096; i += blockDim.x) v |= mask[i] & 0xFFFFFF00u;
  if (v) atomicOr(flag, 1);
}

__global__ void combine_kernel(float* out, const float* partb, const float* bout) {
  int i = blockIdx.x * blockDim.x + threadIdx.x;
  out[i] = out[i] + partb[i] + bout[i & 63];
}

__device__ __forceinline__ float sel8(const float* a, int idx) {
  float v = a[0];
#pragma unroll
  for (int i = 1; i < 8; ++i) v = (idx == i) ? a[i] : v;
  return v;
}

// System-scope relaxed store (proven R7-R10).
__device__ __forceinline__ void st_sys(float* p, float v) {
  __hip_atomic_store(p, v, __ATOMIC_RELAXED, __HIP_MEMORY_SCOPE_SYSTEM);
}
__device__ __forceinline__ void st_sys_i(int* p, int v) {
  __hip_atomic_store(p, v, __ATOMIC_RELAXED, __HIP_MEMORY_SCOPE_SYSTEM);
}

// 32-member barrier: R9 slot signal + R10 buffer_inv acquire (proven).
// Entry __syncthreads drains st_sys stores AND the memory-side atomicAdds
// (global_atomic without return is vmcnt-tracked; R8's RMW-arrival barrier
// proved pollers observe RMWs only after memory-side execution).
__device__ __forceinline__ void gbar(int* slots, int hs, int nbar) {
  __syncthreads();
  if (threadIdx.x < 64) {
    if (threadIdx.x == 0) st_sys_i(slots + hs * 16, nbar);
    const int* myslot = slots + (threadIdx.x & 31) * 16;
    for (;;) {
      int v = __hip_atomic_load(myslot, __ATOMIC_RELAXED, __HIP_MEMORY_SCOPE_AGENT);
      if (__all(v >= nbar)) break;
      __builtin_amdgcn_s_sleep(1);
    }
    asm volatile("buffer_inv\n\ts_waitcnt vmcnt(0)" ::: "memory");
  }
  __syncthreads();
}

// one j-step of the gh loop (R10): h row [j][bA..bA+8], scalar weights
#define GH_STEP(C, JOFF) {                                                   \
  const float* hr = hrd + (size_t)(j0 + jj + (JOFF)) * Bx + bA;              \
  float4 ha  = *(const float4*)(hr);                                         \
  float4 hbv = *(const float4*)(hr + 4);                                     \
  float s0 = w0.C, s1 = w1.C, s2 = w2.C;                                     \
  acc0[0]=fmaf(s0,ha.x,acc0[0]);  acc0[1]=fmaf(s0,ha.y,acc0[1]);             \
  acc0[2]=fmaf(s0,ha.z,acc0[2]);  acc0[3]=fmaf(s0,ha.w,acc0[3]);             \
  acc0[4]=fmaf(s0,hbv.x,acc0[4]); acc0[5]=fmaf(s0,hbv.y,acc0[5]);            \
  acc0[6]=fmaf(s0,hbv.z,acc0[6]); acc0[7]=fmaf(s0,hbv.w,acc0[7]);            \
  acc1[0]=fmaf(s1,ha.x,acc1[0]);  acc1[1]=fmaf(s1,ha.y,acc1[1]);             \
  acc1[2]=fmaf(s1,ha.z,acc1[2]);  acc1[3]=fmaf(s1,ha.w,acc1[3]);             \
  acc1[4]=fmaf(s1,hbv.x,acc1[4]); acc1[5]=fmaf(s1,hbv.y,acc1[5]);            \
  acc1[6]=fmaf(s1,hbv.z,acc1[6]); acc1[7]=fmaf(s1,hbv.w,acc1[7]);            \
  acc3[0]=fmaf(s2,ha.x,acc3[0]);  acc3[1]=fmaf(s2,ha.y,acc3[1]);             \
  acc3[2]=fmaf(s2,ha.z,acc3[2]);  acc3[3]=fmaf(s2,ha.w,acc3[3]);             \
  acc3[4]=fmaf(s2,hbv.x,acc3[4]); acc3[5]=fmaf(s2,hbv.y,acc3[5]);            \
  acc3[6]=fmaf(s2,hbv.z,acc3[6]); acc3[7]=fmaf(s2,hbv.w,acc3[7]); }

__global__ void __launch_bounds__(512, 2)
birnn_main(BParams p) {
  extern __shared__ float lds[];

  const int w   = blockIdx.x;
  const int g   = w & 7;         // group = (dir, batch-group)
  const int dir = g >> 2;
  const int bg  = g & 3;
  const int hs  = w >> 3;        // hidden slice 0..31 (= slot index)
  const int b0  = bg * 32;
  const int u0  = hs * 16;
  const int f0  = hs * 2;
  const int tid = threadIdx.x;

  const float* Wih = dir ? p.Wih_b : p.Wih_f;
  const float* Whh = dir ? p.Whh_b : p.Whh_f;
  const float* bih = dir ? p.bih_b : p.bih_f;
  const float* bhh = dir ? p.bhh_b : p.bhh_f;
  const float* Wro = dir ? p.Wro_b : p.Wro_f;
  const float* bro = dir ? p.bro_b : p.bro_f;

  float* hbuf  = p.ws + H_OFF;    // [dir*2+ping][u][b]
  float* xhb4  = p.ws + XHB_OFF;  // [4 ping][dir][b][f], atomic accumulator
  int*   slots = (int*)(p.ws + BAR_OFF) + g * 512;
  const int u8f = *(const int*)(p.ws + FLAG_OFF);
  const unsigned char* m8  = (const unsigned char*)p.mask;
  const int*           m32 = (const int*)p.mask;

  float* pout   = dir ? (p.ws + PARTB_OFF) : p.out;
  float* out_xh = p.out + (size_t)(1 + dir) * Bx * Sx * Fx;

  // ---- preload LDS weight slices ----
  for (int idx = tid; idx < 3 * 16 * 512; idx += 512) {
    int g3 = idx >> 13; int rem = idx & 8191;
    int u = rem >> 9;   int j = rem & 511;
    lds[LDSW_WHH + ((g3 * 16 + u) * 8 + (j >> 6)) * 68 + (j & 63)] =
        Whh[(size_t)(g3 * 512 + u0 + u) * Hx + j];
  }
  for (int idx = tid; idx < 2 * 512; idx += 512) {
    int f = idx >> 9, j = idx & 511;
    lds[LDSW_WRO  + f * 544 + (j >> 6) * 68 + (j & 63)] = Wro[(size_t)(f0 + f) * Hx + j];
    lds[LDSW_WOUT + f * 544 + (j >> 6) * 68 + (j & 63)] =
        p.Wout[(size_t)(f0 + f) * (2 * Hx) + dir * Hx + j];
  }
  // Wro slice [64 f][u0..u0+15], stride 17 (bank-spread)
  for (int idx = tid; idx < 64 * 16; idx += 512) {
    int f = idx >> 4, u = idx & 15;
    lds[LDSW_WROS + f * 17 + u] = Wro[(size_t)f * Hx + u0 + u];
  }

  // ---- init: h_0 = 0 (ping 0); xhb all 4 pings = bro ----
  if (hs == 0) {
    for (int idx = tid; idx < 32 * 512; idx += 512) {
      int u = idx >> 5, bo = idx & 31;
      st_sys(&hbuf[((size_t)(dir * 2 + 0) * Hx + u) * Bx + b0 + bo], 0.f);
    }
  }
  float bro_own = 0.f;
  if (tid < 64) {
    bro_own = bro[tid];
#pragma unroll
    for (int q = 0; q < 4; ++q)
      st_sys(&xhb4[(((size_t)q * 2 + dir) * Bx + (b0 + hs)) * Fx + tid], bro_own);
  }

  // phase-A map (R10)
  const int jq   = tid & 7;
  const int ulo  = (tid >> 3) & 7;
  const int wv   = tid >> 6;
  const int bsub = wv & 3;
  const int uhi  = wv >> 2;
  const int u    = uhi * 8 + ulo;
  const int bA   = b0 + bsub * 8;
  const int ru   = u0 + u;
  const int j0   = jq * 64;
  // phase-B/pout map (R10)
  const int blo  = (tid >> 3) & 7;
  const int bB   = b0 + (wv & 3) * 8 + blo;
  const int fB   = wv >> 2;
  // partials map: f = tid&63, batch-quad = tid>>6
  const int pf   = tid & 63;
  const int pbq  = tid >> 6;

  float4 wih0[4], wih1[4], wih2[4];
#pragma unroll
  for (int q = 0; q < 4; ++q) {
    wih0[q] = *(const float4*)(Wih + (size_t)(0 * 512 + ru) * Xx + jq * 16 + q * 4);
    wih1[q] = *(const float4*)(Wih + (size_t)(1 * 512 + ru) * Xx + jq * 16 + q * 4);
    wih2[q] = *(const float4*)(Wih + (size_t)(2 * 512 + ru) * Xx + jq * 16 + q * 4);
  }
  const float bs_r = bih[ru] + bhh[ru];
  const float bs_z = bih[512 + ru] + bhh[512 + ru];
  const float bs_i = bih[1024 + ru];
  const float bs_h = bhh[1024 + ru];

  const float* w0p = lds + LDSW_WHH + ((0 * 16 + u) * 8 + jq) * 68;
  const float* w1p = lds + LDSW_WHH + ((1 * 16 + u) * 8 + jq) * 68;
  const float* w2p = lds + LDSW_WHH + ((2 * 16 + u) * 8 + jq) * 68;

  float hprev_own = 0.f;

  int nbar = 1;
  gbar(slots, hs, nbar);   // publish init (h_0, xhb=bro)

  for (int k = 1; k < Sx; ++k) {
    const int pp = k & 1, pr = pp ^ 1;
    const int t_in = dir ? (Sx - k) : (k - 1);
    const int rdq = (k - 1) & 3;   // xhb ping holding xhat_{k-1}
    const int adq = k & 3;         // xhb ping receiving xhat_k partials
    const int inq = (k + 2) & 3;   // xhb ping to re-init to bro

    // ---- staging: x_in = [blend(x, xhat_{k-1}), m] -> LDS ----
    {
      int bl = tid >> 4, sub = tid & 15;
      int b = b0 + bl;
      float* xr = lds + LDSW_XIN + bl * 160 + (sub >> 1) * 20 + (sub & 1) * 8;
      float v[8];
      if (sub < 8) {
        size_t base = ((size_t)b * Sx + t_in) * Fx + sub * 8;
        float4 xa = *(const float4*)(p.x + base);
        float4 xb = *(const float4*)(p.x + base + 4);
        const float* xhp = xhb4 + (((size_t)rdq * 2 + dir) * Bx + b) * Fx + sub * 8;
        float4 ha  = *(const float4*)(xhp);
        float4 hb4 = *(const float4*)(xhp + 4);
        int mi[8];
        if (u8f) {
          unsigned long long mm = *(const unsigned long long*)(m8 + base);
#pragma unroll
          for (int j = 0; j < 8; ++j) mi[j] = (int)((mm >> (8 * j)) & 0xFF);
        } else {
          int4 ma = *(const int4*)(m32 + base);
          int4 mb = *(const int4*)(m32 + base + 4);
          mi[0] = ma.x; mi[1] = ma.y; mi[2] = ma.z; mi[3] = ma.w;
          mi[4] = mb.x; mi[5] = mb.y; mi[6] = mb.z; mi[7] = mb.w;
        }
        v[0] = mi[0] ? xa.x : ha.x;  v[1] = mi[1] ? xa.y : ha.y;
        v[2] = mi[2] ? xa.z : ha.z;  v[3] = mi[3] ? xa.w : ha.w;
        v[4] = mi[4] ? xb.x : hb4.x; v[5] = mi[5] ? xb.y : hb4.y;
        v[6] = mi[6] ? xb.z : hb4.z; v[7] = mi[7] ? xb.w : hb4.w;
      } else {
        size_t base = ((size_t)b * Sx + t_in) * Fx + (sub - 8) * 8;
        if (u8f) {
          unsigned long long mm = *(const unsigned long long*)(m8 + base);
#pragma unroll
          for (int j = 0; j < 8; ++j) v[j] = (float)((mm >> (8 * j)) & 0xFF);
        } else {
          int4 ma = *(const int4*)(m32 + base);
          int4 mb = *(const int4*)(m32 + base + 4);
          v[0] = (float)ma.x; v[1] = (float)ma.y; v[2] = (float)ma.z; v[3] = (float)ma.w;
          v[4] = (float)mb.x; v[5] = (float)mb.y; v[6] = (float)mb.z; v[7] = (float)mb.w;
        }
      }
      *(float4*)(xr)     = make_float4(v[0], v[1], v[2], v[3]);
      *(float4*)(xr + 4) = make_float4(v[4], v[5], v[6], v[7]);
    }
    // ---- out_xh copy for own batch (xhat_{k-1} at T=t_in) ----
    if (tid < 64) {
      float v = xhb4[(((size_t)rdq * 2 + dir) * Bx + (b0 + hs)) * Fx + tid];
      st_sys(&out_xh[((size_t)(b0 + hs) * Sx + t_in) * Fx + tid], v);
    }
    // ---- pout distributed (T=t_in, from h_{k-1}) ----
    {
      const float* hnw  = hbuf + (size_t)(dir * 2 + pr) * Hx * Bx;
      const float* wouL = lds + LDSW_WOUT + fB * 544 + jq * 68;
      const float* hcol = hnw + (size_t)j0 * Bx + bB;
      float ap = 0.f;
#pragma unroll 4
      for (int jj = 0; jj < 64; jj += 4) {
        float4 wp = *(const float4*)(wouL + jj);
        float h0 = hcol[(size_t)(jj + 0) * Bx];
        float h1 = hcol[(size_t)(jj + 1) * Bx];
        float h2 = hcol[(size_t)(jj + 2) * Bx];
        float h3 = hcol[(size_t)(jj + 3) * Bx];
        ap = fmaf(wp.x, h0, ap); ap = fmaf(wp.y, h1, ap);
        ap = fmaf(wp.z, h2, ap); ap = fmaf(wp.w, h3, ap);
      }
#pragma unroll
      for (int m = 1; m <= 4; m <<= 1) ap += __shfl_xor(ap, m);
      if (jq == 0)
        st_sys(&pout[((size_t)bB * Sx + t_in) * Fx + f0 + fB], ap);
    }
    __syncthreads();

    float acc0[8], acc1[8], acc2[8], acc3[8];
#pragma unroll
    for (int i = 0; i < 8; ++i) { acc0[i] = 0.f; acc1[i] = 0.f; acc2[i] = 0.f; acc3[i] = 0.f; }

    // ---- gh: Whh (LDS) x h_{k-1} ([u][b], R10) ----
    {
      const float* hrd = hbuf + (size_t)(dir * 2 + pr) * Hx * Bx;
#pragma unroll 2
      for (int jj = 0; jj < 64; jj += 4) {
        float4 w0 = *(const float4*)(w0p + jj);
        float4 w1 = *(const float4*)(w1p + jj);
        float4 w2 = *(const float4*)(w2p + jj);
        GH_STEP(x, 0)
        GH_STEP(y, 1)
        GH_STEP(z, 2)
        GH_STEP(w, 3)
      }
    }
    // ---- gi: Wih (regs) x x_in (LDS) (R10) ----
    {
      const float* xinb = lds + LDSW_XIN;
#pragma unroll
      for (int q = 0; q < 4; ++q) {
        float4 w0 = wih0[q], w1 = wih1[q], w2 = wih2[q];
        int off = jq * 20 + q * 4;
#pragma unroll
        for (int bb = 0; bb < 8; ++bb) {
          float4 xv = *(const float4*)(xinb + (bsub * 8 + bb) * 160 + off);
          acc0[bb] = fmaf(w0.x, xv.x, acc0[bb]); acc0[bb] = fmaf(w0.y, xv.y, acc0[bb]);
          acc0[bb] = fmaf(w0.z, xv.z, acc0[bb]); acc0[bb] = fmaf(w0.w, xv.w, acc0[bb]);
          acc1[bb] = fmaf(w1.x, xv.x, acc1[bb]); acc1[bb] = fmaf(w1.y, xv.y, acc1[bb]);
          acc1[bb] = fmaf(w1.z, xv.z, acc1[bb]); acc1[bb] = fmaf(w1.w, xv.w, acc1[bb]);
          acc2[bb] = fmaf(w2.x, xv.x, acc2[bb]); acc2[bb] = fmaf(w2.y, xv.y, acc2[bb]);
          acc2[bb] = fmaf(w2.z, xv.z, acc2[bb]); acc2[bb] = fmaf(w2.w, xv.w, acc2[bb]);
        }
      }
    }
#pragma unroll
    for (int m = 1; m <= 4; m <<= 1) {
#pragma unroll
      for (int bb = 0; bb < 8; ++bb) {
        acc0[bb] += __shfl_xor(acc0[bb], m);
        acc1[bb] += __shfl_xor(acc1[bb], m);
        acc2[bb] += __shfl_xor(acc2[bb], m);
        acc3[bb] += __shfl_xor(acc3[bb], m);
      }
    }
    // ---- gates: h_k -> global ([u][b], 32B chunks) + LDS slice bounce ----
    {
      int b = bA + jq;
      float sr  = sel8(acc0, jq);
      float sz  = sel8(acc1, jq);
      float sgi = sel8(acc2, jq);
      float sgh = sel8(acc3, jq);
      float r = 1.f / (1.f + __expf(-(sr + bs_r)));
      float z = 1.f / (1.f + __expf(-(sz + bs_z)));
      float n = tanhf(sgi + bs_i + r * (sgh + bs_h));
      float hn = (1.f - z) * n + z * hprev_own;
      hprev_own = hn;
      st_sys(&hbuf[((size_t)(dir * 2 + pp) * Hx + ru) * Bx + b], hn);
      lds[LDSW_HX + (bsub * 8 + jq) * 16 + u] = hn;
    }
    __syncthreads();

    // ---- xhat_k partials: Wro[64f][16u-slice] . h_k-slice -> atomicAdd ----
    {
      const float* wros = lds + LDSW_WROS + pf * 17;
      float* xq = xhb4 + (((size_t)adq * 2 + dir) * Bx + b0) * Fx;
#pragma unroll
      for (int i = 0; i < 4; ++i) {
        int bl = pbq * 4 + i;
        const float* hx = lds + LDSW_HX + bl * 16;
        float s = 0.f;
#pragma unroll
        for (int uu = 0; uu < 16; ++uu) s = fmaf(wros[uu], hx[uu], s);
        atomicAdd(xq + (size_t)bl * Fx + pf, s);
      }
    }
    // ---- re-init ping (k+2)&3 to bro (race-free: 4-deep ring) ----
    if (tid < 64)
      st_sys(&xhb4[(((size_t)inq * 2 + dir) * Bx + (b0 + hs)) * Fx + tid], bro_own);

    ++nbar;
    gbar(slots, hs, nbar);   // ONE barrier per step
  }

  // ---- epilogue: outputs for h_{S-1} (T = dir ? 0 : S-1), R10 phase-B ----
  {
    const int ppE = (Sx - 1) & 1;
    const int tE  = dir ? 0 : (Sx - 1);
    const float* hnw  = hbuf + (size_t)(dir * 2 + ppE) * Hx * Bx;
    const float* wroL = lds + LDSW_WRO  + fB * 544 + jq * 68;
    const float* wouL = lds + LDSW_WOUT + fB * 544 + jq * 68;
    const float* hcol = hnw + (size_t)j0 * Bx + bB;
    float ax = 0.f, ap = 0.f;
#pragma unroll 4
    for (int jj = 0; jj < 64; jj += 4) {
      float4 wx = *(const float4*)(wroL + jj);
      float4 wp = *(const float4*)(wouL + jj);
      float h0 = hcol[(size_t)(jj + 0) * Bx];
      float h1 = hcol[(size_t)(jj + 1) * Bx];
      float h2 = hcol[(size_t)(jj + 2) * Bx];
      float h3 = hcol[(size_t)(jj + 3) * Bx];
      ax = fmaf(wx.x, h0, ax); ap = fmaf(wp.x, h0, ap);
      ax = fmaf(wx.y, h1, ax); ap = fmaf(wp.y, h1, ap);
      ax = fmaf(wx.z, h2, ax); ap = fmaf(wp.z, h2, ap);
      ax = fmaf(wx.w, h3, ax); ap = fmaf(wp.w, h3, ap);
    }
#pragma unroll
    for (int m = 1; m <= 4; m <<= 1) {
      ax += __shfl_xor(ax, m);
      ap += __shfl_xor(ap, m);
    }
    const int f = f0 + fB;
    if (jq == 0)
      st_sys(&out_xh[((size_t)bB * Sx + tE) * Fx + f], ax + bro[f]);
    else if (jq == 1)
      st_sys(&pout[((size_t)bB * Sx + tE) * Fx + f], ap);
  }
}

extern "C" void kernel_launch(void* const* d_in, const int* in_sizes, int n_in,
                              void* d_out, int out_size, void* d_ws, size_t ws_size,
                              hipStream_t stream) {
  (void)in_sizes; (void)n_in; (void)out_size; (void)ws_size;
  float* ws = (float*)d_ws;

  detect_kernel<<<1, 512, 0, stream>>>((const unsigned int*)d_in[1], ws);

  BParams p;
  p.x     = (const float*)d_in[0];  p.mask = d_in[1];
  p.Wih_f = (const float*)d_in[2];  p.Whh_f = (const float*)d_in[3];
  p.bih_f = (const float*)d_in[4];  p.bhh_f = (const float*)d_in[5];
  p.Wro_f = (const float*)d_in[6];  p.bro_f = (const float*)d_in[7];
  p.Wih_b = (const float*)d_in[8];  p.Whh_b = (const float*)d_in[9];
  p.bih_b = (const float*)d_in[10]; p.bhh_b = (const float*)d_in[11];
  p.Wro_b = (const float*)d_in[12]; p.bro_b = (const float*)d_in[13];
  p.Wout  = (const float*)d_in[14]; p.bout  = (const float*)d_in[15];
  p.out   = (float*)d_out;
  p.ws    = ws;

  hipFuncSetAttribute(reinterpret_cast<const void*>(birnn_main),
                      hipFuncAttributeMaxDynamicSharedMemorySize,
                      (int)(LDSW_TOTAL * sizeof(float)));
  void* args[] = { (void*)&p };
  hipLaunchCooperativeKernel(reinterpret_cast<void*>(birnn_main),
                             dim3(256), dim3(512), args,
                             (unsigned)(LDSW_TOTAL * sizeof(float)), stream);

  combine_kernel<<<dim3(Bx * Sx * Fx / 256), dim3(256), 0, stream>>>(
      (float*)d_out, ws + PARTB_OFF, (const float*)d_in[15]);
}

// Round 15
// 18395.164 us; speedup vs baseline: 2.6017x; 1.1487x over previous
//
#include <hip/hip_runtime.h>

#define Bx 128
#define Sx 512
#define Fx 64
#define Hx 512
#define Xx 128   // 2F

// ---- workspace float offsets ----
#define PARTB_OFF 0ull                               // bwd Wout-partial [B][S][F]
#define H_OFF     ((size_t)Bx * Sx * Fx)             // h [2dir*2ping][u][b]
#define XHB_OFF   (H_OFF + (size_t)2 * 2 * Hx * Bx)  // xhat acc [4 ping][2 dir][b][f]
#define BAR_OFF   (XHB_OFF + (size_t)4 * 2 * Bx * Fx)
#define FLAG_OFF  (BAR_OFF + 4096)

// ---- LDS word offsets ----
#define LDSW_WHH   0                            // [3][16][8][68] = 26112
#define LDSW_XIN   26112                        // [32 b][8 chunks][20] = 5120
#define LDSW_WRO   (LDSW_XIN + 32 * 160)        // full rows (epilogue) 2x544
#define LDSW_WROS  (LDSW_WRO + 2 * 544)         // Wro  slice [64 f][17]
#define LDSW_WOUTS (LDSW_WROS + 1088)           // Wout slice [64 f][17]
#define LDSW_HX    (LDSW_WOUTS + 1088)          // h slice bounce [32 b][16 u]
#define LDSW_TOTAL (LDSW_HX + 512 + 16)         // 35040 floats = 140.2KB -> 1 wg/CU

struct BParams {
  const float* x; const void* mask;
  const float* Wih_f; const float* Whh_f; const float* bih_f; const float* bhh_f;
  const float* Wro_f; const float* bro_f;
  const float* Wih_b; const float* Whh_b; const float* bih_b; const float* bhh_b;
  const float* Wro_b; const float* bro_b;
  const float* Wout; const float* bout;
  float* out; float* ws;
};

__global__ void detect_kernel(const unsigned int* mask, float* ws) {
  int* bars = (int*)(ws + BAR_OFF);
  int* flag = (int*)(ws + FLAG_OFF);
  int t = threadIdx.x;
  for (int i = t; i < 4096; i += blockDim.x) bars[i] = 0;
  if (t == 0) *flag = 0;
  __syncthreads();
  unsigned int v = 0;
  for (int i = t; i < 4096; i += blockDim.x) v |= mask[i] & 0xFFFFFF00u;
  if (v) atomicOr(flag, 1);
}

// zero both pout atomic targets (graph-replay safe: runs every launch)
__global__ void init_kernel(float* out, float* partb) {
  size_t i = (size_t)blockIdx.x * blockDim.x + threadIdx.x;
  const size_t n = (size_t)Bx * Sx * Fx / 4;
  if (i < n) {
    ((float4*)out)[i]   = make_float4(0.f, 0.f, 0.f, 0.f);
    ((float4*)partb)[i] = make_float4(0.f, 0.f, 0.f, 0.f);
  }
}

__global__ void combine_kernel(float* out, const float* partb, const float* bout) {
  int i = blockIdx.x * blockDim.x + threadIdx.x;
  out[i] = out[i] + partb[i] + bout[i & 63];
}

__device__ __forceinline__ float sel8(const float* a, int idx) {
  float v = a[0];
#pragma unroll
  for (int i = 1; i < 8; ++i) v = (idx == i) ? a[i] : v;
  return v;
}

// System-scope relaxed store (proven R7-R14).
__device__ __forceinline__ void st_sys(float* p, float v) {
  __hip_atomic_store(p, v, __ATOMIC_RELAXED, __HIP_MEMORY_SCOPE_SYSTEM);
}
__device__ __forceinline__ void st_sys_i(int* p, int v) {
  __hip_atomic_store(p, v, __ATOMIC_RELAXED, __HIP_MEMORY_SCOPE_SYSTEM);
}

// 32-member barrier: R9 slot signal + R10 buffer_inv acquire (proven).
// Entry __syncthreads drains st_sys stores AND memory-side atomicAdds.
__device__ __forceinline__ void gbar(int* slots, int hs, int nbar) {
  __syncthreads();
  if (threadIdx.x < 64) {
    if (threadIdx.x == 0) st_sys_i(slots + hs * 16, nbar);
    const int* myslot = slots + (threadIdx.x & 31) * 16;
    for (;;) {
      int v = __hip_atomic_load(myslot, __ATOMIC_RELAXED, __HIP_MEMORY_SCOPE_AGENT);
      if (__all(v >= nbar)) break;
      __builtin_amdgcn_s_sleep(1);
    }
    asm volatile("buffer_inv\n\ts_waitcnt vmcnt(0)" ::: "memory");
  }
  __syncthreads();
}

// one j-step of the gh loop (R10/R14)
#define GH_STEP(C, JOFF) {                                                   \
  const float* hr = hrd + (size_t)(j0 + jj + (JOFF)) * Bx + bA;              \
  float4 ha  = *(const float4*)(hr);                                         \
  float4 hbv = *(const float4*)(hr + 4);                                     \
  float s0 = w0.C, s1 = w1.C, s2 = w2.C;                                     \
  acc0[0]=fmaf(s0,ha.x,acc0[0]);  acc0[1]=fmaf(s0,ha.y,acc0[1]);             \
  acc0[2]=fmaf(s0,ha.z,acc0[2]);  acc0[3]=fmaf(s0,ha.w,acc0[3]);             \
  acc0[4]=fmaf(s0,hbv.x,acc0[4]); acc0[5]=fmaf(s0,hbv.y,acc0[5]);            \
  acc0[6]=fmaf(s0,hbv.z,acc0[6]); acc0[7]=fmaf(s0,hbv.w,acc0[7]);            \
  acc1[0]=fmaf(s1,ha.x,acc1[0]);  acc1[1]=fmaf(s1,ha.y,acc1[1]);             \
  acc1[2]=fmaf(s1,ha.z,acc1[2]);  acc1[3]=fmaf(s1,ha.w,acc1[3]);             \
  acc1[4]=fmaf(s1,hbv.x,acc1[4]); acc1[5]=fmaf(s1,hbv.y,acc1[5]);            \
  acc1[6]=fmaf(s1,hbv.z,acc1[6]); acc1[7]=fmaf(s1,hbv.w,acc1[7]);            \
  acc3[0]=fmaf(s2,ha.x,acc3[0]);  acc3[1]=fmaf(s2,ha.y,acc3[1]);             \
  acc3[2]=fmaf(s2,ha.z,acc3[2]);  acc3[3]=fmaf(s2,ha.w,acc3[3]);             \
  acc3[4]=fmaf(s2,hbv.x,acc3[4]); acc3[5]=fmaf(s2,hbv.y,acc3[5]);            \
  acc3[6]=fmaf(s2,hbv.z,acc3[6]); acc3[7]=fmaf(s2,hbv.w,acc3[7]); }

__global__ void __launch_bounds__(512, 2)
birnn_main(BParams p) {
  extern __shared__ float lds[];

  const int w   = blockIdx.x;
  const int g   = w & 7;         // group = (dir, batch-group)
  const int dir = g >> 2;
  const int bg  = g & 3;
  const int hs  = w >> 3;        // hidden slice 0..31 (= slot index)
  const int b0  = bg * 32;
  const int u0  = hs * 16;
  const int f0  = hs * 2;
  const int tid = threadIdx.x;

  const float* Wih = dir ? p.Wih_b : p.Wih_f;
  const float* Whh = dir ? p.Whh_b : p.Whh_f;
  const float* bih = dir ? p.bih_b : p.bih_f;
  const float* bhh = dir ? p.bhh_b : p.bhh_f;
  const float* Wro = dir ? p.Wro_b : p.Wro_f;
  const float* bro = dir ? p.bro_b : p.bro_f;

  float* hbuf  = p.ws + H_OFF;    // [dir*2+ping][u][b]
  float* xhb4  = p.ws + XHB_OFF;  // [4 ping][dir][b][f], atomic accumulator
  int*   slots = (int*)(p.ws + BAR_OFF) + g * 512;
  const int u8f = *(const int*)(p.ws + FLAG_OFF);
  const unsigned char* m8  = (const unsigned char*)p.mask;
  const int*           m32 = (const int*)p.mask;

  float* pout   = dir ? (p.ws + PARTB_OFF) : p.out;   // zero-initialized
  float* out_xh = p.out + (size_t)(1 + dir) * Bx * Sx * Fx;

  // ---- preload LDS weight slices ----
  for (int idx = tid; idx < 3 * 16 * 512; idx += 512) {
    int g3 = idx >> 13; int rem = idx & 8191;
    int u = rem >> 9;   int j = rem & 511;
    lds[LDSW_WHH + ((g3 * 16 + u) * 8 + (j >> 6)) * 68 + (j & 63)] =
        Whh[(size_t)(g3 * 512 + u0 + u) * Hx + j];
  }
  for (int idx = tid; idx < 2 * 512; idx += 512) {
    int f = idx >> 9, j = idx & 511;
    lds[LDSW_WRO + f * 544 + (j >> 6) * 68 + (j & 63)] = Wro[(size_t)(f0 + f) * Hx + j];
  }
  // Wro / Wout_half slices [64 f][u0..u0+15], stride 17
  for (int idx = tid; idx < 64 * 16; idx += 512) {
    int f = idx >> 4, u = idx & 15;
    lds[LDSW_WROS  + f * 17 + u] = Wro[(size_t)f * Hx + u0 + u];
    lds[LDSW_WOUTS + f * 17 + u] = p.Wout[(size_t)f * (2 * Hx) + dir * Hx + u0 + u];
  }

  // ---- init: h_0 = 0 (ping 0); xhb all 4 pings = bro ----
  if (hs == 0) {
    for (int idx = tid; idx < 32 * 512; idx += 512) {
      int u = idx >> 5, bo = idx & 31;
      st_sys(&hbuf[((size_t)(dir * 2 + 0) * Hx + u) * Bx + b0 + bo], 0.f);
    }
  }
  float bro_own = 0.f;
  if (tid < 64) {
    bro_own = bro[tid];
#pragma unroll
    for (int q = 0; q < 4; ++q)
      st_sys(&xhb4[(((size_t)q * 2 + dir) * Bx + (b0 + hs)) * Fx + tid], bro_own);
  }

  // phase-A map (R10/R14)
  const int jq   = tid & 7;
  const int ulo  = (tid >> 3) & 7;
  const int wv   = tid >> 6;
  const int bsub = wv & 3;
  const int uhi  = wv >> 2;
  const int u    = uhi * 8 + ulo;
  const int bA   = b0 + bsub * 8;
  const int ru   = u0 + u;
  const int j0   = jq * 64;
  // epilogue map (R14 phase-B shape)
  const int blo  = (tid >> 3) & 7;
  const int bB   = b0 + (wv & 3) * 8 + blo;
  const int fB   = wv >> 2;
  // partials map: f = tid&63, batch-quad = tid>>6
  const int pf   = tid & 63;
  const int pbq  = tid >> 6;

  float4 wih0[4], wih1[4], wih2[4];
#pragma unroll
  for (int q = 0; q < 4; ++q) {
    wih0[q] = *(const float4*)(Wih + (size_t)(0 * 512 + ru) * Xx + jq * 16 + q * 4);
    wih1[q] = *(const float4*)(Wih + (size_t)(1 * 512 + ru) * Xx + jq * 16 + q * 4);
    wih2[q] = *(const float4*)(Wih + (size_t)(2 * 512 + ru) * Xx + jq * 16 + q * 4);
  }
  const float bs_r = bih[ru] + bhh[ru];
  const float bs_z = bih[512 + ru] + bhh[512 + ru];
  const float bs_i = bih[1024 + ru];
  const float bs_h = bhh[1024 + ru];

  const float* w0p = lds + LDSW_WHH + ((0 * 16 + u) * 8 + jq) * 68;
  const float* w1p = lds + LDSW_WHH + ((1 * 16 + u) * 8 + jq) * 68;
  const float* w2p = lds + LDSW_WHH + ((2 * 16 + u) * 8 + jq) * 68;

  float hprev_own = 0.f;

  int nbar = 1;
  gbar(slots, hs, nbar);   // publish init (h_0, xhb=bro)

  for (int k = 1; k < Sx; ++k) {
    const int pp = k & 1, pr = pp ^ 1;
    const int t_in = dir ? (Sx - k) : (k - 1);
    const int T_k  = dir ? (Sx - 1 - k) : k;   // T index of h_k
    const int rdq = (k - 1) & 3;   // xhb ping holding xhat_{k-1}
    const int adq = k & 3;         // xhb ping receiving xhat_k partials
    const int inq = (k + 2) & 3;   // xhb ping to re-init to bro

    // ---- staging: x_in = [blend(x, xhat_{k-1}), m] -> LDS ----
    {
      int bl = tid >> 4, sub = tid & 15;
      int b = b0 + bl;
      float* xr = lds + LDSW_XIN + bl * 160 + (sub >> 1) * 20 + (sub & 1) * 8;
      float v[8];
      if (sub < 8) {
        size_t base = ((size_t)b * Sx + t_in) * Fx + sub * 8;
        float4 xa = *(const float4*)(p.x + base);
        float4 xb = *(const float4*)(p.x + base + 4);
        const float* xhp = xhb4 + (((size_t)rdq * 2 + dir) * Bx + b) * Fx + sub * 8;
        float4 ha  = *(const float4*)(xhp);
        float4 hb4 = *(const float4*)(xhp + 4);
        int mi[8];
        if (u8f) {
          unsigned long long mm = *(const unsigned long long*)(m8 + base);
#pragma unroll
          for (int j = 0; j < 8; ++j) mi[j] = (int)((mm >> (8 * j)) & 0xFF);
        } else {
          int4 ma = *(const int4*)(m32 + base);
          int4 mb = *(const int4*)(m32 + base + 4);
          mi[0] = ma.x; mi[1] = ma.y; mi[2] = ma.z; mi[3] = ma.w;
          mi[4] = mb.x; mi[5] = mb.y; mi[6] = mb.z; mi[7] = mb.w;
        }
        v[0] = mi[0] ? xa.x : ha.x;  v[1] = mi[1] ? xa.y : ha.y;
        v[2] = mi[2] ? xa.z : ha.z;  v[3] = mi[3] ? xa.w : ha.w;
        v[4] = mi[4] ? xb.x : hb4.x; v[5] = mi[5] ? xb.y : hb4.y;
        v[6] = mi[6] ? xb.z : hb4.z; v[7] = mi[7] ? xb.w : hb4.w;
      } else {
        size_t base = ((size_t)b * Sx + t_in) * Fx + (sub - 8) * 8;
        if (u8f) {
          unsigned long long mm = *(const unsigned long long*)(m8 + base);
#pragma unroll
          for (int j = 0; j < 8; ++j) v[j] = (float)((mm >> (8 * j)) & 0xFF);
        } else {
          int4 ma = *(const int4*)(m32 + base);
          int4 mb = *(const int4*)(m32 + base + 4);
          v[0] = (float)ma.x; v[1] = (float)ma.y; v[2] = (float)ma.z; v[3] = (float)ma.w;
          v[4] = (float)mb.x; v[5] = (float)mb.y; v[6] = (float)mb.z; v[7] = (float)mb.w;
        }
      }
      *(float4*)(xr)     = make_float4(v[0], v[1], v[2], v[3]);
      *(float4*)(xr + 4) = make_float4(v[4], v[5], v[6], v[7]);
    }
    // ---- out_xh copy for own batch (xhat_{k-1} at T=t_in) ----
    if (tid < 64) {
      float v = xhb4[(((size_t)rdq * 2 + dir) * Bx + (b0 + hs)) * Fx + tid];
      st_sys(&out_xh[((size_t)(b0 + hs) * Sx + t_in) * Fx + tid], v);
    }
    __syncthreads();

    float acc0[8], acc1[8], acc2[8], acc3[8];
#pragma unroll
    for (int i = 0; i < 8; ++i) { acc0[i] = 0.f; acc1[i] = 0.f; acc2[i] = 0.f; acc3[i] = 0.f; }

    // ---- gh: Whh (LDS) x h_{k-1} ([u][b], R10) ----
    {
      const float* hrd = hbuf + (size_t)(dir * 2 + pr) * Hx * Bx;
#pragma unroll 2
      for (int jj = 0; jj < 64; jj += 4) {
        float4 w0 = *(const float4*)(w0p + jj);
        float4 w1 = *(const float4*)(w1p + jj);
        float4 w2 = *(const float4*)(w2p + jj);
        GH_STEP(x, 0)
        GH_STEP(y, 1)
        GH_STEP(z, 2)
        GH_STEP(w, 3)
      }
    }
    // ---- gi: Wih (regs) x x_in (LDS) ----
    {
      const float* xinb = lds + LDSW_XIN;
#pragma unroll
      for (int q = 0; q < 4; ++q) {
        float4 w0 = wih0[q], w1 = wih1[q], w2 = wih2[q];
        int off = jq * 20 + q * 4;
#pragma unroll
        for (int bb = 0; bb < 8; ++bb) {
          float4 xv = *(const float4*)(xinb + (bsub * 8 + bb) * 160 + off);
          acc0[bb] = fmaf(w0.x, xv.x, acc0[bb]); acc0[bb] = fmaf(w0.y, xv.y, acc0[bb]);
          acc0[bb] = fmaf(w0.z, xv.z, acc0[bb]); acc0[bb] = fmaf(w0.w, xv.w, acc0[bb]);
          acc1[bb] = fmaf(w1.x, xv.x, acc1[bb]); acc1[bb] = fmaf(w1.y, xv.y, acc1[bb]);
          acc1[bb] = fmaf(w1.z, xv.z, acc1[bb]); acc1[bb] = fmaf(w1.w, xv.w, acc1[bb]);
          acc2[bb] = fmaf(w2.x, xv.x, acc2[bb]); acc2[bb] = fmaf(w2.y, xv.y, acc2[bb]);
          acc2[bb] = fmaf(w2.z, xv.z, acc2[bb]); acc2[bb] = fmaf(w2.w, xv.w, acc2[bb]);
        }
      }
    }
#pragma unroll
    for (int m = 1; m <= 4; m <<= 1) {
#pragma unroll
      for (int bb = 0; bb < 8; ++bb) {
        acc0[bb] += __shfl_xor(acc0[bb], m);
        acc1[bb] += __shfl_xor(acc1[bb], m);
        acc2[bb] += __shfl_xor(acc2[bb], m);
        acc3[bb] += __shfl_xor(acc3[bb], m);
      }
    }
    // ---- gates: h_k -> global ([u][b]) + LDS slice bounce ----
    {
      int b = bA + jq;
      float sr  = sel8(acc0, jq);
      float sz  = sel8(acc1, jq);
      float sgi = sel8(acc2, jq);
      float sgh = sel8(acc3, jq);
      float r = 1.f / (1.f + __expf(-(sr + bs_r)));
      float z = 1.f / (1.f + __expf(-(sz + bs_z)));
      float n = tanhf(sgi + bs_i + r * (sgh + bs_h));
      float hn = (1.f - z) * n + z * hprev_own;
      hprev_own = hn;
      st_sys(&hbuf[((size_t)(dir * 2 + pp) * Hx + ru) * Bx + b], hn);
      lds[LDSW_HX + (bsub * 8 + jq) * 16 + u] = hn;
    }
    __syncthreads();

    // ---- partials from h_k slice: xhat (ring) AND pout (final T) ----
    {
      const float* wros = lds + LDSW_WROS  + pf * 17;
      const float* wout = lds + LDSW_WOUTS + pf * 17;
      float* xq = xhb4 + (((size_t)adq * 2 + dir) * Bx + b0) * Fx;
#pragma unroll
      for (int i = 0; i < 4; ++i) {
        int bl = pbq * 4 + i;
        const float* hx = lds + LDSW_HX + bl * 16;
        float s = 0.f, s2 = 0.f;
#pragma unroll
        for (int uu = 0; uu < 16; ++uu) {
          float hv = hx[uu];
          s  = fmaf(wros[uu], hv, s);
          s2 = fmaf(wout[uu], hv, s2);
        }
        atomicAdd(xq + (size_t)bl * Fx + pf, s);
        atomicAdd(pout + ((size_t)(b0 + bl) * Sx + T_k) * Fx + pf, s2);
      }
    }
    // ---- re-init ping (k+2)&3 to bro (race-free: 4-deep ring) ----
    if (tid < 64)
      st_sys(&xhb4[(((size_t)inq * 2 + dir) * Bx + (b0 + hs)) * Fx + tid], bro_own);

    ++nbar;
    gbar(slots, hs, nbar);   // ONE barrier per step
  }

  // ---- epilogue: out_xh for h_{S-1} (T = dir ? 0 : S-1) ----
  {
    const int ppE = (Sx - 1) & 1;
    const int tE  = dir ? 0 : (Sx - 1);
    const float* hnw  = hbuf + (size_t)(dir * 2 + ppE) * Hx * Bx;
    const float* wroL = lds + LDSW_WRO + fB * 544 + jq * 68;
    const float* hcol = hnw + (size_t)j0 * Bx + bB;
    float ax = 0.f;
#pragma unroll 4
    for (int jj = 0; jj < 64; jj += 4) {
      float4 wx = *(const float4*)(wroL + jj);
      ax = fmaf(wx.x, hcol[(size_t)(jj + 0) * Bx], ax);
      ax = fmaf(wx.y, hcol[(size_t)(jj + 1) * Bx], ax);
      ax = fmaf(wx.z, hcol[(size_t)(jj + 2) * Bx], ax);
      ax = fmaf(wx.w, hcol[(size_t)(jj + 3) * Bx], ax);
    }
#pragma unroll
    for (int m = 1; m <= 4; m <<= 1) ax += __shfl_xor(ax, m);
    const int f = f0 + fB;
    if (jq == 0)
      st_sys(&out_xh[((size_t)bB * Sx + tE) * Fx + f], ax + bro[f]);
  }
}

extern "C" void kernel_launch(void* const* d_in, const int* in_sizes, int n_in,
                              void* d_out, int out_size, void* d_ws, size_t ws_size,
                              hipStream_t stream) {
  (void)in_sizes; (void)n_in; (void)out_size; (void)ws_size;
  float* ws = (float*)d_ws;

  detect_kernel<<<1, 512, 0, stream>>>((const unsigned int*)d_in[1], ws);
  init_kernel<<<(Bx * Sx * Fx / 4 + 255) / 256, 256, 0, stream>>>(
      (float*)d_out, ws + PARTB_OFF);

  BParams p;
  p.x     = (const float*)d_in[0];  p.mask = d_in[1];
  p.Wih_f = (const float*)d_in[2];  p.Whh_f = (const float*)d_in[3];
  p.bih_f = (const float*)d_in[4];  p.bhh_f = (const float*)d_in[5];
  p.Wro_f = (const float*)d_in[6];  p.bro_f = (const float*)d_in[7];
  p.Wih_b = (const float*)d_in[8];  p.Whh_b = (const float*)d_in[9];
  p.bih_b = (const float*)d_in[10]; p.bhh_b = (const float*)d_in[11];
  p.Wro_b = (const float*)d_in[12]; p.bro_b = (const float*)d_in[13];
  p.Wout  = (const float*)d_in[14]; p.bout  = (const float*)d_in[15];
  p.out   = (float*)d_out;
  p.ws    = ws;

  hipFuncSetAttribute(reinterpret_cast<const void*>(birnn_main),
                      hipFuncAttributeMaxDynamicSharedMemorySize,
                      (int)(LDSW_TOTAL * sizeof(float)));
  void* args[] = { (void*)&p };
  hipLaunchCooperativeKernel(reinterpret_cast<void*>(birnn_main),
                             dim3(256), dim3(512), args,
                             (unsigned)(LDSW_TOTAL * sizeof(float)), stream);

  combine_kernel<<<dim3(Bx * Sx * Fx / 256), dim3(256), 0, stream>>>(
      (float*)d_out, ws + PARTB_OFF, (const float*)d_in[15]);
}

// Round 18
// 18384.512 us; speedup vs baseline: 2.6032x; 1.0006x over previous
//
#include <hip/hip_runtime.h>

#define Bx 128
#define Sx 512
#define Fx 64
#define Hx 512
#define Xx 128   // 2F

// ---- unified workspace float offsets (both kernels) ----
#define PARTB_OFF 0ull                               // bwd Wout-partial [B][S][F]
#define H_OFF     ((size_t)Bx * Sx * Fx)             // h [2dir*2ping][u][b]
#define XHB_OFF   (H_OFF + (size_t)2 * 2 * Hx * Bx)  // xhat acc [4 ping][2 dir][b][f]
#define BAR_OFF   (XHB_OFF + (size_t)4 * 2 * Bx * Fx)// 8192 ints
#define FLAG_OFF  (BAR_OFF + 8192)

// ---- R15 kernel LDS (512-thread wg, 16-unit slice) — proven 18.4ms ----
#define LDSW_WHH   0
#define LDSW_XIN   26112
#define LDSW_WRO   (LDSW_XIN + 32 * 160)
#define LDSW_WROS  (LDSW_WRO + 2 * 544)
#define LDSW_WOUTS (LDSW_WROS + 1088)
#define LDSW_HX    (LDSW_WOUTS + 1088)
#define LDSW_TOTAL (LDSW_HX + 512 + 16)         // 35024 floats = 140.1KB

// ---- V2 kernel LDS (256-thread wg, 8-unit slice, 2 wg/CU target) ----
// Only gates r,z of Whh in LDS; n-gate rows read from global (L2-warm).
#define V2_WHH    0                             // [2][8][8][68] = 8704
#define V2_XIN    8704                          // [32 b][8 chunks][20] = 5120
#define V2_WROS   (V2_XIN + 5120)               // [64 f][9] = 576
#define V2_WOUTS  (V2_WROS + 576)               // [64 f][9] = 576
#define V2_HX     (V2_WOUTS + 576)              // [32 b][8 u] = 256
#define V2_TOTAL  (V2_HX + 256 + 16)            // 15248 floats = 61.0KB < 64KB

struct BParams {
  const float* x; const void* mask;
  const float* Wih_f; const float* Whh_f; const float* bih_f; const float* bhh_f;
  const float* Wro_f; const float* bro_f;
  const float* Wih_b; const float* Whh_b; const float* bih_b; const float* bhh_b;
  const float* Wro_b; const float* bro_b;
  const float* Wout; const float* bout;
  float* out; float* ws;
};

__global__ void detect_kernel(const unsigned int* mask, float* ws) {
  int* bars = (int*)(ws + BAR_OFF);
  int* flag = (int*)(ws + FLAG_OFF);
  int t = threadIdx.x;
  for (int i = t; i < 8192; i += blockDim.x) bars[i] = 0;
  if (t == 0) *flag = 0;
  __syncthreads();
  unsigned int v = 0;
  for (int i = t; i < 4096; i += blockDim.x) v |= mask[i] & 0xFFFFFF00u;
  if (v) atomicOr(flag, 1);
}

__global__ void init_kernel(float* out, float* partb) {
  size_t i = (size_t)blockIdx.x * blockDim.x + threadIdx.x;
  const size_t n = (size_t)Bx * Sx * Fx / 4;
  if (i < n) {
    ((float4*)out)[i]   = make_float4(0.f, 0.f, 0.f, 0.f);
    ((float4*)partb)[i] = make_float4(0.f, 0.f, 0.f, 0.f);
  }
}

__global__ void combine_kernel(float* out, const float* partb, const float* bout) {
  int i = blockIdx.x * blockDim.x + threadIdx.x;
  out[i] = out[i] + partb[i] + bout[i & 63];
}

__device__ __forceinline__ float sel8(const float* a, int idx) {
  float v = a[0];
#pragma unroll
  for (int i = 1; i < 8; ++i) v = (idx == i) ? a[i] : v;
  return v;
}

__device__ __forceinline__ void st_sys(float* p, float v) {
  __hip_atomic_store(p, v, __ATOMIC_RELAXED, __HIP_MEMORY_SCOPE_SYSTEM);
}
__device__ __forceinline__ void st_sys_i(int* p, int v) {
  __hip_atomic_store(p, v, __ATOMIC_RELAXED, __HIP_MEMORY_SCOPE_SYSTEM);
}

// 32-member barrier (R15, proven)
__device__ __forceinline__ void gbar32(int* slots, int hs, int nbar) {
  __syncthreads();
  if (threadIdx.x < 64) {
    if (threadIdx.x == 0) st_sys_i(slots + hs * 16, nbar);
    const int* myslot = slots + (threadIdx.x & 31) * 16;
    for (;;) {
      int v = __hip_atomic_load(myslot, __ATOMIC_RELAXED, __HIP_MEMORY_SCOPE_AGENT);
      if (__all(v >= nbar)) break;
      __builtin_amdgcn_s_sleep(1);
    }
    asm volatile("buffer_inv\n\ts_waitcnt vmcnt(0)" ::: "memory");
  }
  __syncthreads();
}

// 64-member barrier (v2)
__device__ __forceinline__ void gbar64(int* slots, int hs, int nbar) {
  __syncthreads();
  if (threadIdx.x < 64) {
    if (threadIdx.x == 0) st_sys_i(slots + hs * 16, nbar);
    const int* myslot = slots + threadIdx.x * 16;
    for (;;) {
      int v = __hip_atomic_load(myslot, __ATOMIC_RELAXED, __HIP_MEMORY_SCOPE_AGENT);
      if (__all(v >= nbar)) break;
      __builtin_amdgcn_s_sleep(1);
    }
    asm volatile("buffer_inv\n\ts_waitcnt vmcnt(0)" ::: "memory");
  }
  __syncthreads();
}

#define GH_STEP(C, JOFF) {                                                   \
  const float* hr = hrd + (size_t)(j0 + jj + (JOFF)) * Bx + bA;              \
  float4 ha  = *(const float4*)(hr);                                         \
  float4 hbv = *(const float4*)(hr + 4);                                     \
  float s0 = w0.C, s1 = w1.C, s2 = w2.C;                                     \
  acc0[0]=fmaf(s0,ha.x,acc0[0]);  acc0[1]=fmaf(s0,ha.y,acc0[1]);             \
  acc0[2]=fmaf(s0,ha.z,acc0[2]);  acc0[3]=fmaf(s0,ha.w,acc0[3]);             \
  acc0[4]=fmaf(s0,hbv.x,acc0[4]); acc0[5]=fmaf(s0,hbv.y,acc0[5]);            \
  acc0[6]=fmaf(s0,hbv.z,acc0[6]); acc0[7]=fmaf(s0,hbv.w,acc0[7]);            \
  acc1[0]=fmaf(s1,ha.x,acc1[0]);  acc1[1]=fmaf(s1,ha.y,acc1[1]);             \
  acc1[2]=fmaf(s1,ha.z,acc1[2]);  acc1[3]=fmaf(s1,ha.w,acc1[3]);             \
  acc1[4]=fmaf(s1,hbv.x,acc1[4]); acc1[5]=fmaf(s1,hbv.y,acc1[5]);            \
  acc1[6]=fmaf(s1,hbv.z,acc1[6]); acc1[7]=fmaf(s1,hbv.w,acc1[7]);            \
  acc3[0]=fmaf(s2,ha.x,acc3[0]);  acc3[1]=fmaf(s2,ha.y,acc3[1]);             \
  acc3[2]=fmaf(s2,ha.z,acc3[2]);  acc3[3]=fmaf(s2,ha.w,acc3[3]);             \
  acc3[4]=fmaf(s2,hbv.x,acc3[4]); acc3[5]=fmaf(s2,hbv.y,acc3[5]);            \
  acc3[6]=fmaf(s2,hbv.z,acc3[6]); acc3[7]=fmaf(s2,hbv.w,acc3[7]); }

// ==================== R15 kernel (verbatim logic; proven) ====================
__global__ void __launch_bounds__(512, 2)
birnn_r15(BParams p) {
  extern __shared__ float lds[];

  const int w   = blockIdx.x;
  const int g   = w & 7;
  const int dir = g >> 2;
  const int bg  = g & 3;
  const int hs  = w >> 3;
  const int b0  = bg * 32;
  const int u0  = hs * 16;
  const int tid = threadIdx.x;

  const float* Wih = dir ? p.Wih_b : p.Wih_f;
  const float* Whh = dir ? p.Whh_b : p.Whh_f;
  const float* bih = dir ? p.bih_b : p.bih_f;
  const float* bhh = dir ? p.bhh_b : p.bhh_f;
  const float* Wro = dir ? p.Wro_b : p.Wro_f;
  const float* bro = dir ? p.bro_b : p.bro_f;

  float* hbuf  = p.ws + H_OFF;
  float* xhb4  = p.ws + XHB_OFF;
  int*   slots = (int*)(p.ws + BAR_OFF) + g * 512;
  const int u8f = *(const int*)(p.ws + FLAG_OFF);
  const unsigned char* m8  = (const unsigned char*)p.mask;
  const int*           m32 = (const int*)p.mask;

  float* pout   = dir ? (p.ws + PARTB_OFF) : p.out;
  float* out_xh = p.out + (size_t)(1 + dir) * Bx * Sx * Fx;

  for (int idx = tid; idx < 3 * 16 * 512; idx += 512) {
    int g3 = idx >> 13; int rem = idx & 8191;
    int u = rem >> 9;   int j = rem & 511;
    lds[LDSW_WHH + ((g3 * 16 + u) * 8 + (j >> 6)) * 68 + (j & 63)] =
        Whh[(size_t)(g3 * 512 + u0 + u) * Hx + j];
  }
  for (int idx = tid; idx < 2 * 512; idx += 512) {
    int f = idx >> 9, j = idx & 511;
    lds[LDSW_WRO + f * 544 + (j >> 6) * 68 + (j & 63)] =
        Wro[(size_t)(hs * 2 + f) * Hx + j];
  }
  for (int idx = tid; idx < 64 * 16; idx += 512) {
    int f = idx >> 4, u = idx & 15;
    lds[LDSW_WROS  + f * 17 + u] = Wro[(size_t)f * Hx + u0 + u];
    lds[LDSW_WOUTS + f * 17 + u] = p.Wout[(size_t)f * (2 * Hx) + dir * Hx + u0 + u];
  }

  if (hs == 0) {
    for (int idx = tid; idx < 32 * 512; idx += 512) {
      int u = idx >> 5, bo = idx & 31;
      st_sys(&hbuf[((size_t)(dir * 2 + 0) * Hx + u) * Bx + b0 + bo], 0.f);
    }
  }
  float bro_own = 0.f;
  if (tid < 64) {
    bro_own = bro[tid];
#pragma unroll
    for (int q = 0; q < 4; ++q)
      st_sys(&xhb4[(((size_t)q * 2 + dir) * Bx + (b0 + hs)) * Fx + tid], bro_own);
    int T0 = dir ? (Sx - 1) : 0;
    st_sys(&out_xh[((size_t)(b0 + hs) * Sx + T0) * Fx + tid], bro_own);
  }

  const int jq   = tid & 7;
  const int ulo  = (tid >> 3) & 7;
  const int wv   = tid >> 6;
  const int bsub = wv & 3;
  const int uhi  = wv >> 2;
  const int u    = uhi * 8 + ulo;
  const int bA   = b0 + bsub * 8;
  const int ru   = u0 + u;
  const int j0   = jq * 64;
  const int blo  = (tid >> 3) & 7;
  const int bB   = b0 + (wv & 3) * 8 + blo;
  const int fB   = wv >> 2;
  const int pf   = tid & 63;
  const int pbq  = tid >> 6;

  float4 wih0[4], wih1[4], wih2[4];
#pragma unroll
  for (int q = 0; q < 4; ++q) {
    wih0[q] = *(const float4*)(Wih + (size_t)(0 * 512 + ru) * Xx + jq * 16 + q * 4);
    wih1[q] = *(const float4*)(Wih + (size_t)(1 * 512 + ru) * Xx + jq * 16 + q * 4);
    wih2[q] = *(const float4*)(Wih + (size_t)(2 * 512 + ru) * Xx + jq * 16 + q * 4);
  }
  const float bs_r = bih[ru] + bhh[ru];
  const float bs_z = bih[512 + ru] + bhh[512 + ru];
  const float bs_i = bih[1024 + ru];
  const float bs_h = bhh[1024 + ru];

  const float* w0p = lds + LDSW_WHH + ((0 * 16 + u) * 8 + jq) * 68;
  const float* w1p = lds + LDSW_WHH + ((1 * 16 + u) * 8 + jq) * 68;
  const float* w2p = lds + LDSW_WHH + ((2 * 16 + u) * 8 + jq) * 68;

  float hprev_own = 0.f;

  int nbar = 1;
  gbar32(slots, hs, nbar);

  for (int k = 1; k < Sx; ++k) {
    const int pp = k & 1, pr = pp ^ 1;
    const int t_in = dir ? (Sx - k) : (k - 1);
    const int T_k  = dir ? (Sx - 1 - k) : k;
    const int rdq = (k - 1) & 3;
    const int adq = k & 3;
    const int inq = (k + 2) & 3;

    {
      int bl = tid >> 4, sub = tid & 15;
      int b = b0 + bl;
      float* xr = lds + LDSW_XIN + bl * 160 + (sub >> 1) * 20 + (sub & 1) * 8;
      float v[8];
      if (sub < 8) {
        size_t base = ((size_t)b * Sx + t_in) * Fx + sub * 8;
        float4 xa = *(const float4*)(p.x + base);
        float4 xb = *(const float4*)(p.x + base + 4);
        const float* xhp = xhb4 + (((size_t)rdq * 2 + dir) * Bx + b) * Fx + sub * 8;
        float4 ha  = *(const float4*)(xhp);
        float4 hb4 = *(const float4*)(xhp + 4);
        int mi[8];
        if (u8f) {
          unsigned long long mm = *(const unsigned long long*)(m8 + base);
#pragma unroll
          for (int j = 0; j < 8; ++j) mi[j] = (int)((mm >> (8 * j)) & 0xFF);
        } else {
          int4 ma = *(const int4*)(m32 + base);
          int4 mb = *(const int4*)(m32 + base + 4);
          mi[0] = ma.x; mi[1] = ma.y; mi[2] = ma.z; mi[3] = ma.w;
          mi[4] = mb.x; mi[5] = mb.y; mi[6] = mb.z; mi[7] = mb.w;
        }
        v[0] = mi[0] ? xa.x : ha.x;  v[1] = mi[1] ? xa.y : ha.y;
        v[2] = mi[2] ? xa.z : ha.z;  v[3] = mi[3] ? xa.w : ha.w;
        v[4] = mi[4] ? xb.x : hb4.x; v[5] = mi[5] ? xb.y : hb4.y;
        v[6] = mi[6] ? xb.z : hb4.z; v[7] = mi[7] ? xb.w : hb4.w;
      } else {
        size_t base = ((size_t)b * Sx + t_in) * Fx + (sub - 8) * 8;
        if (u8f) {
          unsigned long long mm = *(const unsigned long long*)(m8 + base);
#pragma unroll
          for (int j = 0; j < 8; ++j) v[j] = (float)((mm >> (8 * j)) & 0xFF);
        } else {
          int4 ma = *(const int4*)(m32 + base);
          int4 mb = *(const int4*)(m32 + base + 4);
          v[0] = (float)ma.x; v[1] = (float)ma.y; v[2] = (float)ma.z; v[3] = (float)ma.w;
          v[4] = (float)mb.x; v[5] = (float)mb.y; v[6] = (float)mb.z; v[7] = (float)mb.w;
        }
      }
      *(float4*)(xr)     = make_float4(v[0], v[1], v[2], v[3]);
      *(float4*)(xr + 4) = make_float4(v[4], v[5], v[6], v[7]);
    }
    if (tid < 64) {
      float v = xhb4[(((size_t)rdq * 2 + dir) * Bx + (b0 + hs)) * Fx + tid];
      st_sys(&out_xh[((size_t)(b0 + hs) * Sx + t_in) * Fx + tid], v);
    }
    __syncthreads();

    float acc0[8], acc1[8], acc2[8], acc3[8];
#pragma unroll
    for (int i = 0; i < 8; ++i) { acc0[i] = 0.f; acc1[i] = 0.f; acc2[i] = 0.f; acc3[i] = 0.f; }

    {
      const float* hrd = hbuf + (size_t)(dir * 2 + pr) * Hx * Bx;
#pragma unroll 2
      for (int jj = 0; jj < 64; jj += 4) {
        float4 w0 = *(const float4*)(w0p + jj);
        float4 w1 = *(const float4*)(w1p + jj);
        float4 w2 = *(const float4*)(w2p + jj);
        GH_STEP(x, 0)
        GH_STEP(y, 1)
        GH_STEP(z, 2)
        GH_STEP(w, 3)
      }
    }
    {
      const float* xinb = lds + LDSW_XIN;
#pragma unroll
      for (int q = 0; q < 4; ++q) {
        float4 w0 = wih0[q], w1 = wih1[q], w2 = wih2[q];
        int off = jq * 20 + q * 4;
#pragma unroll
        for (int bb = 0; bb < 8; ++bb) {
          float4 xv = *(const float4*)(xinb + (bsub * 8 + bb) * 160 + off);
          acc0[bb] = fmaf(w0.x, xv.x, acc0[bb]); acc0[bb] = fmaf(w0.y, xv.y, acc0[bb]);
          acc0[bb] = fmaf(w0.z, xv.z, acc0[bb]); acc0[bb] = fmaf(w0.w, xv.w, acc0[bb]);
          acc1[bb] = fmaf(w1.x, xv.x, acc1[bb]); acc1[bb] = fmaf(w1.y, xv.y, acc1[bb]);
          acc1[bb] = fmaf(w1.z, xv.z, acc1[bb]); acc1[bb] = fmaf(w1.w, xv.w, acc1[bb]);
          acc2[bb] = fmaf(w2.x, xv.x, acc2[bb]); acc2[bb] = fmaf(w2.y, xv.y, acc2[bb]);
          acc2[bb] = fmaf(w2.z, xv.z, acc2[bb]); acc2[bb] = fmaf(w2.w, xv.w, acc2[bb]);
        }
      }
    }
#pragma unroll
    for (int m = 1; m <= 4; m <<= 1) {
#pragma unroll
      for (int bb = 0; bb < 8; ++bb) {
        acc0[bb] += __shfl_xor(acc0[bb], m);
        acc1[bb] += __shfl_xor(acc1[bb], m);
        acc2[bb] += __shfl_xor(acc2[bb], m);
        acc3[bb] += __shfl_xor(acc3[bb], m);
      }
    }
    {
      int b = bA + jq;
      float sr  = sel8(acc0, jq);
      float sz  = sel8(acc1, jq);
      float sgi = sel8(acc2, jq);
      float sgh = sel8(acc3, jq);
      float r = 1.f / (1.f + __expf(-(sr + bs_r)));
      float z = 1.f / (1.f + __expf(-(sz + bs_z)));
      float n = tanhf(sgi + bs_i + r * (sgh + bs_h));
      float hn = (1.f - z) * n + z * hprev_own;
      hprev_own = hn;
      st_sys(&hbuf[((size_t)(dir * 2 + pp) * Hx + ru) * Bx + b], hn);
      lds[LDSW_HX + (bsub * 8 + jq) * 16 + u] = hn;
    }
    __syncthreads();

    {
      const float* wros = lds + LDSW_WROS  + pf * 17;
      const float* wout = lds + LDSW_WOUTS + pf * 17;
      float* xq = xhb4 + (((size_t)adq * 2 + dir) * Bx + b0) * Fx;
#pragma unroll
      for (int i = 0; i < 4; ++i) {
        int bl = pbq * 4 + i;
        const float* hx = lds + LDSW_HX + bl * 16;
        float s = 0.f, s2 = 0.f;
#pragma unroll
        for (int uu = 0; uu < 16; ++uu) {
          float hv = hx[uu];
          s  = fmaf(wros[uu], hv, s);
          s2 = fmaf(wout[uu], hv, s2);
        }
        atomicAdd(xq + (size_t)bl * Fx + pf, s);
        atomicAdd(pout + ((size_t)(b0 + bl) * Sx + T_k) * Fx + pf, s2);
      }
    }
    if (tid < 64)
      st_sys(&xhb4[(((size_t)inq * 2 + dir) * Bx + (b0 + hs)) * Fx + tid], bro_own);

    ++nbar;
    gbar32(slots, hs, nbar);
  }

  {
    const int ppE = (Sx - 1) & 1;
    const int tE  = dir ? 0 : (Sx - 1);
    const float* hnw  = hbuf + (size_t)(dir * 2 + ppE) * Hx * Bx;
    const float* wroL = lds + LDSW_WRO + fB * 544 + jq * 68;
    const float* hcol = hnw + (size_t)j0 * Bx + bB;
    float ax = 0.f;
#pragma unroll 4
    for (int jj = 0; jj < 64; jj += 4) {
      float4 wx = *(const float4*)(wroL + jj);
      ax = fmaf(wx.x, hcol[(size_t)(jj + 0) * Bx], ax);
      ax = fmaf(wx.y, hcol[(size_t)(jj + 1) * Bx], ax);
      ax = fmaf(wx.z, hcol[(size_t)(jj + 2) * Bx], ax);
      ax = fmaf(wx.w, hcol[(size_t)(jj + 3) * Bx], ax);
    }
#pragma unroll
    for (int m = 1; m <= 4; m <<= 1) ax += __shfl_xor(ax, m);
    const int f = hs * 2 + fB;
    if (jq == 0)
      st_sys(&out_xh[((size_t)bB * Sx + tE) * Fx + f], ax + bro[f]);
  }
}

// ==================== V2 kernel (2 wg/CU, 61KB LDS) ====================
__global__ void __launch_bounds__(256, 2)
birnn_v2(BParams p) {
  extern __shared__ float lds[];

  const int w   = blockIdx.x;
  const int g   = w & 7;
  const int dir = g >> 2;
  const int bg  = g & 3;
  const int hs  = w >> 3;        // 0..63
  const int b0  = bg * 32;
  const int u0  = hs * 8;
  const int tid = threadIdx.x;

  const float* Wih = dir ? p.Wih_b : p.Wih_f;
  const float* Whh = dir ? p.Whh_b : p.Whh_f;
  const float* bih = dir ? p.bih_b : p.bih_f;
  const float* bhh = dir ? p.bhh_b : p.bhh_f;
  const float* Wro = dir ? p.Wro_b : p.Wro_f;
  const float* bro = dir ? p.bro_b : p.bro_f;

  float* hbuf  = p.ws + H_OFF;
  float* xhb4  = p.ws + XHB_OFF;
  int*   slots = (int*)(p.ws + BAR_OFF) + g * 1024;
  const int u8f = *(const int*)(p.ws + FLAG_OFF);
  const unsigned char* m8  = (const unsigned char*)p.mask;
  const int*           m32 = (const int*)p.mask;

  float* pout   = dir ? (p.ws + PARTB_OFF) : p.out;
  float* out_xh = p.out + (size_t)(1 + dir) * Bx * Sx * Fx;

  // preload: Whh gates r,z only
  for (int idx = tid; idx < 2 * 8 * 512; idx += 256) {
    int g3 = idx >> 12; int rem = idx & 4095;
    int u = rem >> 9;   int j = rem & 511;
    lds[V2_WHH + ((g3 * 8 + u) * 8 + (j >> 6)) * 68 + (j & 63)] =
        Whh[(size_t)(g3 * 512 + u0 + u) * Hx + j];
  }
  for (int idx = tid; idx < 64 * 8; idx += 256) {
    int f = idx >> 3, uu = idx & 7;
    lds[V2_WROS  + f * 9 + uu] = Wro[(size_t)f * Hx + u0 + uu];
    lds[V2_WOUTS + f * 9 + uu] = p.Wout[(size_t)f * (2 * Hx) + dir * Hx + u0 + uu];
  }

  if (hs == 0) {
    for (int idx = tid; idx < 32 * 512; idx += 256) {
      int u = idx >> 5, bo = idx & 31;
      st_sys(&hbuf[((size_t)(dir * 2 + 0) * Hx + u) * Bx + b0 + bo], 0.f);
    }
  }
  const int ownb  = ((hs & 1) == 0);
  const int b_own = b0 + (hs >> 1);
  float bro_own = 0.f;
  if (tid < 64) {
    bro_own = bro[tid];
    if (ownb) {
#pragma unroll
      for (int q = 0; q < 4; ++q)
        st_sys(&xhb4[(((size_t)q * 2 + dir) * Bx + b_own) * Fx + tid], bro_own);
      int T0 = dir ? (Sx - 1) : 0;
      st_sys(&out_xh[((size_t)b_own * Sx + T0) * Fx + tid], bro_own);
    }
  }

  const int jq   = tid & 7;
  const int ulo  = (tid >> 3) & 7;
  const int wv   = tid >> 6;
  const int bsub = wv;
  const int bA   = b0 + bsub * 8;
  const int ru   = u0 + ulo;
  const int j0   = jq * 64;
  const int blo  = (tid >> 3) & 7;
  const int bB   = b0 + wv * 8 + blo;
  const int pf   = tid & 63;
  const int pbq  = tid >> 6;
  const int sbl  = tid >> 3;
  const int ssub = tid & 7;
  const int b_st = b0 + sbl;

  float4 wih0[4], wih1[4], wih2[4];
#pragma unroll
  for (int q = 0; q < 4; ++q) {
    wih0[q] = *(const float4*)(Wih + (size_t)(0 * 512 + ru) * Xx + jq * 16 + q * 4);
    wih1[q] = *(const float4*)(Wih + (size_t)(1 * 512 + ru) * Xx + jq * 16 + q * 4);
    wih2[q] = *(const float4*)(Wih + (size_t)(2 * 512 + ru) * Xx + jq * 16 + q * 4);
  }
  const float bs_r = bih[ru] + bhh[ru];
  const float bs_z = bih[512 + ru] + bhh[512 + ru];
  const float bs_i = bih[1024 + ru];
  const float bs_h = bhh[1024 + ru];

  const float* w0p = lds + V2_WHH + ((0 * 8 + ulo) * 8 + jq) * 68;
  const float* w1p = lds + V2_WHH + ((1 * 8 + ulo) * 8 + jq) * 68;
  const float* w2g = Whh + (size_t)(2 * 512 + ru) * Hx + j0;   // n-gate from L2

  float hprev_own = 0.f;

  int nbar = 1;
  gbar64(slots, hs, nbar);

  for (int k = 1; k < Sx; ++k) {
    const int pp = k & 1, pr = pp ^ 1;
    const int t_in = dir ? (Sx - k) : (k - 1);
    const int T_k  = dir ? (Sx - 1 - k) : k;
    const int rdq = (k - 1) & 3;
    const int adq = k & 3;
    const int inq = (k + 2) & 3;

    {
      float* xr = lds + V2_XIN + sbl * 160 + ssub * 20;
      if (ssub < 4) {
        size_t base = ((size_t)b_st * Sx + t_in) * Fx + ssub * 16;
        float4 x0 = *(const float4*)(p.x + base);
        float4 x1 = *(const float4*)(p.x + base + 4);
        float4 x2 = *(const float4*)(p.x + base + 8);
        float4 x3 = *(const float4*)(p.x + base + 12);
        const float* xhp = xhb4 + (((size_t)rdq * 2 + dir) * Bx + b_st) * Fx + ssub * 16;
        float4 h0 = *(const float4*)(xhp);
        float4 h1 = *(const float4*)(xhp + 4);
        float4 h2 = *(const float4*)(xhp + 8);
        float4 h3 = *(const float4*)(xhp + 12);
        int mi[16];
        if (u8f) {
          unsigned long long ma = *(const unsigned long long*)(m8 + base);
          unsigned long long mb = *(const unsigned long long*)(m8 + base + 8);
#pragma unroll
          for (int j = 0; j < 8; ++j) { mi[j] = (int)((ma >> (8 * j)) & 0xFF);
                                        mi[8 + j] = (int)((mb >> (8 * j)) & 0xFF); }
        } else {
          int4 q0 = *(const int4*)(m32 + base);
          int4 q1 = *(const int4*)(m32 + base + 4);
          int4 q2 = *(const int4*)(m32 + base + 8);
          int4 q3 = *(const int4*)(m32 + base + 12);
          mi[0]=q0.x; mi[1]=q0.y; mi[2]=q0.z; mi[3]=q0.w;
          mi[4]=q1.x; mi[5]=q1.y; mi[6]=q1.z; mi[7]=q1.w;
          mi[8]=q2.x; mi[9]=q2.y; mi[10]=q2.z; mi[11]=q2.w;
          mi[12]=q3.x; mi[13]=q3.y; mi[14]=q3.z; mi[15]=q3.w;
        }
        *(float4*)(xr + 0)  = make_float4(mi[0] ? x0.x : h0.x, mi[1] ? x0.y : h0.y,
                                          mi[2] ? x0.z : h0.z, mi[3] ? x0.w : h0.w);
        *(float4*)(xr + 4)  = make_float4(mi[4] ? x1.x : h1.x, mi[5] ? x1.y : h1.y,
                                          mi[6] ? x1.z : h1.z, mi[7] ? x1.w : h1.w);
        *(float4*)(xr + 8)  = make_float4(mi[8] ? x2.x : h2.x, mi[9] ? x2.y : h2.y,
                                          mi[10] ? x2.z : h2.z, mi[11] ? x2.w : h2.w);
        *(float4*)(xr + 12) = make_float4(mi[12] ? x3.x : h3.x, mi[13] ? x3.y : h3.y,
                                          mi[14] ? x3.z : h3.z, mi[15] ? x3.w : h3.w);
      } else {
        size_t base = ((size_t)b_st * Sx + t_in) * Fx + (ssub - 4) * 16;
        float v[16];
        if (u8f) {
          unsigned long long ma = *(const unsigned long long*)(m8 + base);
          unsigned long long mb = *(const unsigned long long*)(m8 + base + 8);
#pragma unroll
          for (int j = 0; j < 8; ++j) { v[j] = (float)((ma >> (8 * j)) & 0xFF);
                                        v[8 + j] = (float)((mb >> (8 * j)) & 0xFF); }
        } else {
          int4 q0 = *(const int4*)(m32 + base);
          int4 q1 = *(const int4*)(m32 + base + 4);
          int4 q2 = *(const int4*)(m32 + base + 8);
          int4 q3 = *(const int4*)(m32 + base + 12);
          v[0]=(float)q0.x; v[1]=(float)q0.y; v[2]=(float)q0.z; v[3]=(float)q0.w;
          v[4]=(float)q1.x; v[5]=(float)q1.y; v[6]=(float)q1.z; v[7]=(float)q1.w;
          v[8]=(float)q2.x; v[9]=(float)q2.y; v[10]=(float)q2.z; v[11]=(float)q2.w;
          v[12]=(float)q3.x; v[13]=(float)q3.y; v[14]=(float)q3.z; v[15]=(float)q3.w;
        }
        *(float4*)(xr + 0)  = make_float4(v[0], v[1], v[2], v[3]);
        *(float4*)(xr + 4)  = make_float4(v[4], v[5], v[6], v[7]);
        *(float4*)(xr + 8)  = make_float4(v[8], v[9], v[10], v[11]);
        *(float4*)(xr + 12) = make_float4(v[12], v[13], v[14], v[15]);
      }
    }
    if (ownb && tid < 64) {
      float v = xhb4[(((size_t)rdq * 2 + dir) * Bx + b_own) * Fx + tid];
      st_sys(&out_xh[((size_t)b_own * Sx + t_in) * Fx + tid], v);
    }
    __syncthreads();

    float acc0[8], acc1[8], acc2[8], acc3[8];
#pragma unroll
    for (int i = 0; i < 8; ++i) { acc0[i] = 0.f; acc1[i] = 0.f; acc2[i] = 0.f; acc3[i] = 0.f; }

    {
      const float* hrd = hbuf + (size_t)(dir * 2 + pr) * Hx * Bx;
#pragma unroll 4
      for (int jj = 0; jj < 64; jj += 4) {
        float4 w0 = *(const float4*)(w0p + jj);
        float4 w1 = *(const float4*)(w1p + jj);
        float4 w2 = *(const float4*)(w2g + jj);   // n-gate weights from L2
        GH_STEP(x, 0)
        GH_STEP(y, 1)
        GH_STEP(z, 2)
        GH_STEP(w, 3)
      }
    }
    {
      const float* xinb = lds + V2_XIN;
#pragma unroll
      for (int q = 0; q < 4; ++q) {
        float4 w0 = wih0[q], w1 = wih1[q], w2 = wih2[q];
        int off = jq * 20 + q * 4;
#pragma unroll
        for (int bb = 0; bb < 8; ++bb) {
          float4 xv = *(const float4*)(xinb + (bsub * 8 + bb) * 160 + off);
          acc0[bb] = fmaf(w0.x, xv.x, acc0[bb]); acc0[bb] = fmaf(w0.y, xv.y, acc0[bb]);
          acc0[bb] = fmaf(w0.z, xv.z, acc0[bb]); acc0[bb] = fmaf(w0.w, xv.w, acc0[bb]);
          acc1[bb] = fmaf(w1.x, xv.x, acc1[bb]); acc1[bb] = fmaf(w1.y, xv.y, acc1[bb]);
          acc1[bb] = fmaf(w1.z, xv.z, acc1[bb]); acc1[bb] = fmaf(w1.w, xv.w, acc1[bb]);
          acc2[bb] = fmaf(w2.x, xv.x, acc2[bb]); acc2[bb] = fmaf(w2.y, xv.y, acc2[bb]);
          acc2[bb] = fmaf(w2.z, xv.z, acc2[bb]); acc2[bb] = fmaf(w2.w, xv.w, acc2[bb]);
        }
      }
    }
#pragma unroll
    for (int m = 1; m <= 4; m <<= 1) {
#pragma unroll
      for (int bb = 0; bb < 8; ++bb) {
        acc0[bb] += __shfl_xor(acc0[bb], m);
        acc1[bb] += __shfl_xor(acc1[bb], m);
        acc2[bb] += __shfl_xor(acc2[bb], m);
        acc3[bb] += __shfl_xor(acc3[bb], m);
      }
    }
    {
      int b = bA + jq;
      float sr  = sel8(acc0, jq);
      float sz  = sel8(acc1, jq);
      float sgi = sel8(acc2, jq);
      float sgh = sel8(acc3, jq);
      float r = 1.f / (1.f + __expf(-(sr + bs_r)));
      float z = 1.f / (1.f + __expf(-(sz + bs_z)));
      float n = tanhf(sgi + bs_i + r * (sgh + bs_h));
      float hn = (1.f - z) * n + z * hprev_own;
      hprev_own = hn;
      st_sys(&hbuf[((size_t)(dir * 2 + pp) * Hx + ru) * Bx + b], hn);
      lds[V2_HX + (bsub * 8 + jq) * 8 + ulo] = hn;
    }
    __syncthreads();

    {
      const float* wros = lds + V2_WROS  + pf * 9;
      const float* wout = lds + V2_WOUTS + pf * 9;
      float* xq = xhb4 + (((size_t)adq * 2 + dir) * Bx + b0) * Fx;
#pragma unroll
      for (int i = 0; i < 8; ++i) {
        int bl = pbq * 8 + i;
        const float* hx = lds + V2_HX + bl * 8;
        float s = 0.f, s2 = 0.f;
#pragma unroll
        for (int uu = 0; uu < 8; ++uu) {
          float hv = hx[uu];
          s  = fmaf(wros[uu], hv, s);
          s2 = fmaf(wout[uu], hv, s2);
        }
        atomicAdd(xq + (size_t)bl * Fx + pf, s);
        atomicAdd(pout + ((size_t)(b0 + bl) * Sx + T_k) * Fx + pf, s2);
      }
    }
    if (ownb && tid < 64)
      st_sys(&xhb4[(((size_t)inq * 2 + dir) * Bx + b_own) * Fx + tid], bro_own);

    ++nbar;
    gbar64(slots, hs, nbar);
  }

  {
    const int ppE = (Sx - 1) & 1;
    const int tE  = dir ? 0 : (Sx - 1);
    const float* hnw  = hbuf + (size_t)(dir * 2 + ppE) * Hx * Bx;
    const float* wroG = Wro + (size_t)hs * Hx + j0;
    const float* hcol = hnw + (size_t)j0 * Bx + bB;
    float ax = 0.f;
#pragma unroll 4
    for (int jj = 0; jj < 64; jj += 4) {
      float4 wx = *(const float4*)(wroG + jj);
      ax = fmaf(wx.x, hcol[(size_t)(jj + 0) * Bx], ax);
      ax = fmaf(wx.y, hcol[(size_t)(jj + 1) * Bx], ax);
      ax = fmaf(wx.z, hcol[(size_t)(jj + 2) * Bx], ax);
      ax = fmaf(wx.w, hcol[(size_t)(jj + 3) * Bx], ax);
    }
#pragma unroll
    for (int m = 1; m <= 4; m <<= 1) ax += __shfl_xor(ax, m);
    if (jq == 0)
      st_sys(&out_xh[((size_t)bB * Sx + tE) * Fx + hs], ax + bro[hs]);
  }
}

extern "C" void kernel_launch(void* const* d_in, const int* in_sizes, int n_in,
                              void* d_out, int out_size, void* d_ws, size_t ws_size,
                              hipStream_t stream) {
  (void)in_sizes; (void)n_in; (void)out_size; (void)ws_size;
  float* ws = (float*)d_ws;

  detect_kernel<<<1, 512, 0, stream>>>((const unsigned int*)d_in[1], ws);
  init_kernel<<<(Bx * Sx * Fx / 4 + 255) / 256, 256, 0, stream>>>(
      (float*)d_out, ws + PARTB_OFF);

  BParams p;
  p.x     = (const float*)d_in[0];  p.mask = d_in[1];
  p.Wih_f = (const float*)d_in[2];  p.Whh_f = (const float*)d_in[3];
  p.bih_f = (const float*)d_in[4];  p.bhh_f = (const float*)d_in[5];
  p.Wro_f = (const float*)d_in[6];  p.bro_f = (const float*)d_in[7];
  p.Wih_b = (const float*)d_in[8];  p.Whh_b = (const float*)d_in[9];
  p.bih_b = (const float*)d_in[10]; p.bhh_b = (const float*)d_in[11];
  p.Wro_b = (const float*)d_in[12]; p.bro_b = (const float*)d_in[13];
  p.Wout  = (const float*)d_in[14]; p.bout  = (const float*)d_in[15];
  p.out   = (float*)d_out;
  p.ws    = ws;
  void* args[] = { (void*)&p };

  // Deterministic host-side capacity check (pure query, capture-safe):
  // only launch the 512-block variant if >=2 blocks/CU actually fit.
  int nb = 0;
  hipError_t qe = hipOccupancyMaxActiveBlocksPerMultiprocessor(
      &nb, reinterpret_cast<const void*>(birnn_v2), 256,
      (size_t)(V2_TOTAL * sizeof(float)));
  if (qe == hipSuccess && nb >= 2) {
    hipLaunchCooperativeKernel(reinterpret_cast<void*>(birnn_v2),
                               dim3(512), dim3(256), args,
                               (unsigned)(V2_TOTAL * sizeof(float)), stream);
  } else {
    hipFuncSetAttribute(reinterpret_cast<const void*>(birnn_r15),
                        hipFuncAttributeMaxDynamicSharedMemorySize,
                        (int)(LDSW_TOTAL * sizeof(float)));
    hipLaunchCooperativeKernel(reinterpret_cast<void*>(birnn_r15),
                               dim3(256), dim3(512), args,
                               (unsigned)(LDSW_TOTAL * sizeof(float)), stream);
  }

  combine_kernel<<<dim3(Bx * Sx * Fx / 256), dim3(256), 0, stream>>>(
      (float*)d_out, ws + PARTB_OFF, (const float*)d_in[15]);
}